// Round 8
// baseline (4340.162 us; speedup 1.0000x reference)
//
#include <hip/hip_runtime.h>

// Problem constants (from reference)
#define NPTS   8192   // N
#define NPT    2048   // NPOINT
#define NS     32     // NSAMPLE
#define CIN    64
#define BATCH  4
// threshold: f32 nearest to 0.64 (numpy/jax weak-type the python float 0.8**2 to f32)
#define R2     0.64f

// ---------------- prep: transpose weights into ws ----------------
__global__ __launch_bounds__(256) void prep_kernel(const float* __restrict__ w1,
                                                   const float* __restrict__ w2,
                                                   float* __restrict__ w1t,
                                                   float* __restrict__ w2t) {
  int i = blockIdx.x * 256 + threadIdx.x;
  if (i < 128 * 67) {
    int o = i / 67, c = i % 67;
    w1t[c * 128 + o] = w1[i];
  }
  if (i < 256 * 128) {
    int o = i >> 7, c = i & 127;
    w2t[c * 256 + o] = w2[i];
  }
}

// ---------------- Morton sort (u32 keys, in-LDS bitonic) ----------------
__device__ inline uint32_t part1by2(uint32_t x) {
  x &= 1023u;
  x = (x | (x << 16)) & 0x030000FFu;
  x = (x | (x << 8))  & 0x0300F00Fu;
  x = (x | (x << 4))  & 0x030C30C3u;
  x = (x | (x << 2))  & 0x09249249u;
  return x;
}

__device__ inline uint32_t morton3(float x, float y, float z) {
  int qx = (int)((x + 16.f) * 32.f);
  int qy = (int)((y + 16.f) * 32.f);
  int qz = (int)((z + 16.f) * 32.f);
  qx = qx < 0 ? 0 : (qx > 1023 ? 1023 : qx);
  qy = qy < 0 ? 0 : (qy > 1023 ? 1023 : qy);
  qz = qz < 0 ? 0 : (qz > 1023 ? 1023 : qz);
  return part1by2((uint32_t)qx) | (part1by2((uint32_t)qy) << 1) | (part1by2((uint32_t)qz) << 2);
}

// key = (morton top 19 bits << 13) | idx. Sort order only affects clustering
// quality, never correctness (min-updates are exact & order-independent).
__global__ __launch_bounds__(1024) void sort_kernel(const float* __restrict__ xyz,
                                                    float4* __restrict__ sorted) {
  const int b = blockIdx.x;
  const int tid = threadIdx.x;
  const float* X = xyz + (size_t)b * NPTS * 3;
  __shared__ uint32_t S[NPTS];  // 32 KB

  for (int k = 0; k < 8; ++k) {
    int p = tid + (k << 10);
    uint32_t m = morton3(X[p * 3 + 0], X[p * 3 + 1], X[p * 3 + 2]);
    S[p] = ((m >> 11) << 13) | (uint32_t)p;
  }
  __syncthreads();
  for (unsigned k = 2; k <= NPTS; k <<= 1) {
    for (unsigned j = k >> 1; j > 0; j >>= 1) {
      for (int i = tid; i < NPTS; i += 1024) {
        int l = i ^ (int)j;
        if (l > i) {
          uint32_t a = S[i], c = S[l];
          bool sw = ((i & k) == 0) ? (a > c) : (a < c);
          if (sw) { S[i] = c; S[l] = a; }
        }
      }
      __syncthreads();
    }
  }
  for (int k = 0; k < 8; ++k) {
    int pos = tid + (k << 10);
    int o = (int)(S[pos] & 8191u);
    float4 v;
    v.x = X[o * 3 + 0]; v.y = X[o * 3 + 1]; v.z = X[o * 3 + 2];
    v.w = __int_as_float(o);
    sorted[(size_t)b * NPTS + pos] = v;
  }
}

// ---------------- FPS v8: 512 thr, coords in LDS, 16 pts/thread (2x8 clusters) ----
// Bit-exactness (same arguments verified absmax 0.0 in R2/R3/R6/R7):
//  * min-updates use exact-rounded ((dx*dx+dy*dy)+dz*dz); order-independent.
//  * cluster skipped only if 0.9999-scaled conservative bbox lower bound
//    >= cluster max dmin -> skip provably a no-op (1e-4 margin >> 2e-7 rounding).
//  * cached wave (wwm,wwi,wws) reused only when NO lane of the wave burst ->
//    nothing in the wave changed -> identical result. Winner's cluster
//    self-activates next iter (center in bbox -> dlb=0 < cmaxv unless
//    cmaxv==0, in which case the cluster is immutable and skip is safe).
//  * all dists nonneg f32, so u32 order == float order.
//  * tie-breaks -> smallest original index at every stage (numpy argmax):
//    burst uses explicit (dm>mv)||(dm==mv&&oid<mi); wave/block index stages
//    take min oid among value-matching candidates. Winner coords fetched via
//    its sorted position (carried alongside, never part of the comparison).

#define DPP_ROR_U32_MAX4(v)                                                      \
  {                                                                              \
    uint32_t _t;                                                                 \
    _t = (uint32_t)__builtin_amdgcn_update_dpp(0, (int)(v), 0x121, 0xF, 0xF, false); if (_t > (v)) (v) = _t; \
    _t = (uint32_t)__builtin_amdgcn_update_dpp(0, (int)(v), 0x122, 0xF, 0xF, false); if (_t > (v)) (v) = _t; \
    _t = (uint32_t)__builtin_amdgcn_update_dpp(0, (int)(v), 0x124, 0xF, 0xF, false); if (_t > (v)) (v) = _t; \
    _t = (uint32_t)__builtin_amdgcn_update_dpp(0, (int)(v), 0x128, 0xF, 0xF, false); if (_t > (v)) (v) = _t; \
  }

#define DPP_ROR_U32_MAX3(v)                                                      \
  {                                                                              \
    uint32_t _t;                                                                 \
    _t = (uint32_t)__builtin_amdgcn_update_dpp(0, (int)(v), 0x121, 0xF, 0xF, false); if (_t > (v)) (v) = _t; \
    _t = (uint32_t)__builtin_amdgcn_update_dpp(0, (int)(v), 0x122, 0xF, 0xF, false); if (_t > (v)) (v) = _t; \
    _t = (uint32_t)__builtin_amdgcn_update_dpp(0, (int)(v), 0x124, 0xF, 0xF, false); if (_t > (v)) (v) = _t; \
  }

#define DPP_ROR_U32_MIN4(v)                                                      \
  {                                                                              \
    uint32_t _t;                                                                 \
    _t = (uint32_t)__builtin_amdgcn_update_dpp(-1, (int)(v), 0x121, 0xF, 0xF, false); if (_t < (v)) (v) = _t; \
    _t = (uint32_t)__builtin_amdgcn_update_dpp(-1, (int)(v), 0x122, 0xF, 0xF, false); if (_t < (v)) (v) = _t; \
    _t = (uint32_t)__builtin_amdgcn_update_dpp(-1, (int)(v), 0x124, 0xF, 0xF, false); if (_t < (v)) (v) = _t; \
    _t = (uint32_t)__builtin_amdgcn_update_dpp(-1, (int)(v), 0x128, 0xF, 0xF, false); if (_t < (v)) (v) = _t; \
  }

#define DPP_ROR_U32_MIN3(v)                                                      \
  {                                                                              \
    uint32_t _t;                                                                 \
    _t = (uint32_t)__builtin_amdgcn_update_dpp(-1, (int)(v), 0x121, 0xF, 0xF, false); if (_t < (v)) (v) = _t; \
    _t = (uint32_t)__builtin_amdgcn_update_dpp(-1, (int)(v), 0x122, 0xF, 0xF, false); if (_t < (v)) (v) = _t; \
    _t = (uint32_t)__builtin_amdgcn_update_dpp(-1, (int)(v), 0x124, 0xF, 0xF, false); if (_t < (v)) (v) = _t; \
  }

__global__ __launch_bounds__(512) void fps_kernel(const float* __restrict__ xyz,
                                                  const float4* __restrict__ sorted,
                                                  float* __restrict__ new_xyz) {
  const int b = blockIdx.x;
  const int tid = threadIdx.x;     // 0..511
  const int lane = tid & 63;
  const int wv = tid >> 6;         // 0..7
  const float* X = xyz + (size_t)b * NPTS * 3;
  const float4* SP = sorted + (size_t)b * NPTS;

  __shared__ __align__(16) float4 SX[NPTS];        // 128 KB: (x,y,z,oid) morton order
  __shared__ __align__(16) uint4  rec[2][8];

  for (int i = tid; i < NPTS; i += 512) SX[i] = SP[i];
  __syncthreads();

  // per-thread state: dmin in registers, coords stay in LDS
  float dmin[16];
#pragma unroll
  for (int k = 0; k < 16; ++k) dmin[k] = 1e10f;

  float bxmin[2], bxmax[2], bymin[2], bymax[2], bzmin[2], bzmax[2];
  float cmaxv[2]; int cmaxi[2]; int cmspos[2];
#pragma unroll
  for (int c = 0; c < 2; ++c) {
    float4 p0 = SX[tid * 16 + c * 8];
    float xmn = p0.x, xmx = p0.x, ymn = p0.y, ymx = p0.y, zmn = p0.z, zmx = p0.z;
#pragma unroll
    for (int k = 1; k < 8; ++k) {
      float4 p = SX[tid * 16 + c * 8 + k];
      xmn = fminf(xmn, p.x); xmx = fmaxf(xmx, p.x);
      ymn = fminf(ymn, p.y); ymx = fmaxf(ymx, p.y);
      zmn = fminf(zmn, p.z); zmx = fmaxf(zmx, p.z);
    }
    bxmin[c] = xmn; bxmax[c] = xmx;
    bymin[c] = ymn; bymax[c] = ymx;
    bzmin[c] = zmn; bzmax[c] = zmx;
    cmaxv[c] = 1e10f;                       // forces burst at t=1 (dlb <= ~3e3)
    cmaxi[c] = __float_as_int(p0.w);
    cmspos[c] = tid * 16 + c * 8;
  }

  uint32_t wwm = 0u, wwi = 0u, wws = 0u;    // cached wave winner (set at t=1)

  float cx = X[0], cy = X[1], cz = X[2];
  if (tid == 0) {
    new_xyz[(size_t)b * NPT * 3 + 0] = cx;
    new_xyz[(size_t)b * NPT * 3 + 1] = cy;
    new_xyz[(size_t)b * NPT * 3 + 2] = cz;
  }

  for (int t = 1; t < NPT; ++t) {
    // conservative bbox lower bounds for both clusters
    bool act[2];
#pragma unroll
    for (int c = 0; c < 2; ++c) {
      float ex = fmaxf(fmaxf(bxmin[c] - cx, cx - bxmax[c]), 0.f);
      float ey = fmaxf(fmaxf(bymin[c] - cy, cy - bymax[c]), 0.f);
      float ez = fmaxf(fmaxf(bzmin[c] - cz, cz - bzmax[c]), 0.f);
      float dlb = (ex * ex + ey * ey + ez * ez) * 0.9999f;
      act[c] = dlb < cmaxv[c];
    }
    unsigned long long anyact = __ballot(act[0] || act[1]);

    // per-cluster gated bursts (wave skips whole cluster when no lane needs it)
#pragma unroll
    for (int c = 0; c < 2; ++c) {
      if (__ballot(act[c])) {
        if (act[c]) {
          float mv = -1.0f; int mi = 1 << 30; int mk = 0;
#pragma unroll
          for (int k = 0; k < 8; ++k) {
            float4 p = SX[tid * 16 + c * 8 + k];
            float dx = p.x - cx, dy = p.y - cy, dz = p.z - cz;
            float d = __fadd_rn(__fadd_rn(__fmul_rn(dx, dx), __fmul_rn(dy, dy)), __fmul_rn(dz, dz));
            float dm = fminf(dmin[c * 8 + k], d);
            dmin[c * 8 + k] = dm;
            int o = __float_as_int(p.w);
            bool bet = (dm > mv) || (dm == mv && o < mi);
            mv = bet ? dm : mv;
            mi = bet ? o : mi;
            mk = bet ? k : mk;
          }
          cmaxv[c] = mv; cmaxi[c] = mi; cmspos[c] = tid * 16 + c * 8 + mk;
        }
      }
    }

    if (anyact) {
      // thread best = merge of 2 cluster bests (tie: min orig idx)
      float bv = cmaxv[0]; int bi = cmaxi[0]; int bs = cmspos[0];
      {
        bool bet = (cmaxv[1] > bv) || (cmaxv[1] == bv && cmaxi[1] < bi);
        bv = bet ? cmaxv[1] : bv;
        bi = bet ? cmaxi[1] : bi;
        bs = bet ? cmspos[1] : bs;
      }
      // wave value stage
      uint32_t vb = __float_as_uint(bv);
      uint32_t rm = vb;
      DPP_ROR_U32_MAX4(rm)
      uint32_t m0 = (uint32_t)__builtin_amdgcn_readlane((int)rm, 0);
      uint32_t m1 = (uint32_t)__builtin_amdgcn_readlane((int)rm, 16);
      uint32_t m2 = (uint32_t)__builtin_amdgcn_readlane((int)rm, 32);
      uint32_t m3 = (uint32_t)__builtin_amdgcn_readlane((int)rm, 48);
      uint32_t wm = m0 > m1 ? m0 : m1;
      uint32_t wmb = m2 > m3 ? m2 : m3;
      wm = wm > wmb ? wm : wmb;
      // wave index stage (+ sorted-position extraction)
      unsigned long long em = __ballot(vb == wm);
      uint32_t wi, ws;
      if (__popcll(em) == 1) {
        int l = __ffsll(em) - 1;
        wi = (uint32_t)__builtin_amdgcn_readlane(bi, l);
        ws = (uint32_t)__builtin_amdgcn_readlane(bs, l);
      } else {
        uint32_t ik = (vb == wm) ? (uint32_t)bi : 0xFFFFFFFFu;
        DPP_ROR_U32_MIN4(ik)
        uint32_t i0 = (uint32_t)__builtin_amdgcn_readlane((int)ik, 0);
        uint32_t i1 = (uint32_t)__builtin_amdgcn_readlane((int)ik, 16);
        uint32_t i2 = (uint32_t)__builtin_amdgcn_readlane((int)ik, 32);
        uint32_t i3 = (uint32_t)__builtin_amdgcn_readlane((int)ik, 48);
        wi = i0 < i1 ? i0 : i1;
        uint32_t wib = i2 < i3 ? i2 : i3;
        wi = wi < wib ? wi : wib;
        unsigned long long em2 = __ballot(vb == wm && (uint32_t)bi == wi);
        int l2 = __ffsll(em2) - 1;
        ws = (uint32_t)__builtin_amdgcn_readlane(bs, l2);
      }
      wwm = wm; wwi = wi; wws = ws;
    }

    const int buf = t & 1;
    if (lane == 0) { rec[buf][wv] = make_uint4(wwm, wwi, wws, 0u); }
    __syncthreads();

    // block stage: 8 wave-winner slots, lane reads slot (lane&7); rows hold
    // the pattern [0..7,0..7] so ror 1,2,4 covers all 8 slots.
    uint4 r = rec[buf][lane & 7];
    uint32_t bm = r.x;
    DPP_ROR_U32_MAX3(bm)
    uint32_t ci = (r.x == bm) ? r.y : 0xFFFFFFFFu;
    DPP_ROR_U32_MIN3(ci)
    unsigned long long em3 = __ballot(r.x == bm && r.y == ci);
    int l3 = __ffsll(em3) - 1;
    int spos = __builtin_amdgcn_readlane((int)r.z, l3);   // scalar

    float4 wpt = SX[spos];                  // uniform LDS broadcast read
    cx = wpt.x; cy = wpt.y; cz = wpt.z;

    if (tid == 0) {
      float* o = new_xyz + ((size_t)b * NPT + t) * 3;
      o[0] = cx; o[1] = cy; o[2] = cz;
    }
  }
}

// ---------------- ball query: one wave per (b,s) ----------------
__global__ __launch_bounds__(256) void ballquery_kernel(const float* __restrict__ xyz,
                                                        const float* __restrict__ new_xyz,
                                                        int* __restrict__ idx_out) {
  const int w = blockIdx.x * 4 + (threadIdx.x >> 6);   // (b*2048 + s)
  const int lane = threadIdx.x & 63;
  const int b = w >> 11;
  const float* X = xyz + (size_t)b * NPTS * 3;
  const float cx = new_xyz[w * 3 + 0];
  const float cy = new_xyz[w * 3 + 1];
  const float cz = new_xyz[w * 3 + 2];
  int* out = idx_out + (size_t)w * NS;

  int found = 0;
  int first = -1;
  for (int base = 0; base < NPTS; base += 64) {
    const int p = base + lane;
    float x = X[p * 3 + 0], y = X[p * 3 + 1], z = X[p * 3 + 2];
    float dx = x - cx, dy = y - cy, dz = z - cz;
    float d2 = __fadd_rn(__fadd_rn(__fmul_rn(dx, dx), __fmul_rn(dy, dy)), __fmul_rn(dz, dz));
    unsigned long long mask = __ballot(d2 < R2);
    if (mask != 0ull && first < 0) first = base + __ffsll((unsigned long long)mask) - 1;
    if (found < NS) {
      if ((mask >> lane) & 1ull) {
        int rank = found + __popcll(mask & ((1ull << lane) - 1ull));
        if (rank < NS) out[rank] = p;
      }
    }
    found += __popcll(mask);
    if (found >= NS) break;
  }
  if (found < NS) {
    int pad = (first < 0) ? 0 : first;
    if (lane >= found && lane < NS) out[lane] = pad;
  }
}

// ---------------- group + MLP(67->128->256) + maxpool: one block per (b,s) ----------------
__global__ __launch_bounds__(256) void group_mlp_kernel(const float* __restrict__ xyz,
                                                        const float* __restrict__ feat,
                                                        const float* __restrict__ new_xyz,
                                                        const int* __restrict__ idx,
                                                        const float* __restrict__ w1t,
                                                        const float* __restrict__ b1,
                                                        const float* __restrict__ w2t,
                                                        const float* __restrict__ b2,
                                                        float* __restrict__ pooled) {
  const int blk = blockIdx.x;       // b*2048 + s
  const int b = blk >> 11, s = blk & 2047;
  const int tid = threadIdx.x;

  __shared__ __align__(16) float G[67 * 32];    // (C+3) x ns
  __shared__ __align__(16) float H1[128 * 32];  // 128 x ns
  __shared__ int   lidx[NS];
  __shared__ float ctr[3];

  if (tid < NS) lidx[tid] = idx[(size_t)blk * NS + tid];
  if (tid < 3)  ctr[tid] = new_xyz[blk * 3 + tid];
  __syncthreads();

  const float* F = feat + (size_t)b * CIN * NPTS;
  const float* X = xyz + (size_t)b * NPTS * 3;

  for (int e = tid; e < 67 * 32; e += 256) {
    int c = e >> 5, j = e & 31;
    int p = lidx[j];
    float v;
    if (c < 3) v = X[p * 3 + c] - ctr[c];
    else       v = F[(size_t)(c - 3) * NPTS + p];
    G[e] = v;
  }
  __syncthreads();

  // H1 = relu(W1 @ G + b1): 128x32, each thread 4o x 4j
  {
    const int oi = tid >> 3, ji = tid & 7;
    const int o0 = oi * 4, j0 = ji * 4;
    float acc[4][4];
#pragma unroll
    for (int i = 0; i < 4; ++i)
#pragma unroll
      for (int jj = 0; jj < 4; ++jj) acc[i][jj] = 0.f;
#pragma unroll 4
    for (int c = 0; c < 67; ++c) {
      float4 g  = *(const float4*)&G[c * 32 + j0];
      float4 wf = *(const float4*)&w1t[c * 128 + o0];
      float ga[4] = {g.x, g.y, g.z, g.w};
      float wa[4] = {wf.x, wf.y, wf.z, wf.w};
#pragma unroll
      for (int i = 0; i < 4; ++i)
#pragma unroll
        for (int jj = 0; jj < 4; ++jj)
          acc[i][jj] = fmaf(wa[i], ga[jj], acc[i][jj]);
    }
    float4 bb = *(const float4*)&b1[o0];
    float ba[4] = {bb.x, bb.y, bb.z, bb.w};
#pragma unroll
    for (int i = 0; i < 4; ++i) {
      float4 h;
      h.x = fmaxf(acc[i][0] + ba[i], 0.f);
      h.y = fmaxf(acc[i][1] + ba[i], 0.f);
      h.z = fmaxf(acc[i][2] + ba[i], 0.f);
      h.w = fmaxf(acc[i][3] + ba[i], 0.f);
      *(float4*)&H1[(o0 + i) * 32 + j0] = h;
    }
  }
  __syncthreads();

  // H2 = relu(W2 @ H1 + b2): 256x32, each thread 8o x 4j, then maxpool over j
  {
    const int oi = tid >> 3, ji = tid & 7;
    const int o0 = oi * 8, j0 = ji * 4;
    float acc[8][4];
#pragma unroll
    for (int i = 0; i < 8; ++i)
#pragma unroll
      for (int jj = 0; jj < 4; ++jj) acc[i][jj] = 0.f;
#pragma unroll 2
    for (int c = 0; c < 128; ++c) {
      float4 h  = *(const float4*)&H1[c * 32 + j0];
      float4 wa4 = *(const float4*)&w2t[c * 256 + o0];
      float4 wb4 = *(const float4*)&w2t[c * 256 + o0 + 4];
      float ha[4] = {h.x, h.y, h.z, h.w};
      float wa[8] = {wa4.x, wa4.y, wa4.z, wa4.w, wb4.x, wb4.y, wb4.z, wb4.w};
#pragma unroll
      for (int i = 0; i < 8; ++i)
#pragma unroll
        for (int jj = 0; jj < 4; ++jj)
          acc[i][jj] = fmaf(wa[i], ha[jj], acc[i][jj]);
    }
    float4 b2a = *(const float4*)&b2[o0];
    float4 b2b = *(const float4*)&b2[o0 + 4];
    float bb[8] = {b2a.x, b2a.y, b2a.z, b2a.w, b2b.x, b2b.y, b2b.z, b2b.w};
    float m[8];
#pragma unroll
    for (int i = 0; i < 8; ++i) {
      float v0 = fmaxf(acc[i][0] + bb[i], 0.f);
      float v1 = fmaxf(acc[i][1] + bb[i], 0.f);
      float v2 = fmaxf(acc[i][2] + bb[i], 0.f);
      float v3 = fmaxf(acc[i][3] + bb[i], 0.f);
      m[i] = fmaxf(fmaxf(v0, v1), fmaxf(v2, v3));
    }
#pragma unroll
    for (int off = 1; off < 8; off <<= 1)
#pragma unroll
      for (int i = 0; i < 8; ++i) m[i] = fmaxf(m[i], __shfl_xor(m[i], off));
    if (ji == 0) {
#pragma unroll
      for (int i = 0; i < 8; ++i)
        pooled[((size_t)b * 256 + o0 + i) * (size_t)NPT + s] = m[i];
    }
  }
}

extern "C" void kernel_launch(void* const* d_in, const int* in_sizes, int n_in,
                              void* d_out, int out_size, void* d_ws, size_t ws_size,
                              hipStream_t stream) {
  (void)in_sizes; (void)n_in; (void)out_size; (void)ws_size;
  const float* xyz  = (const float*)d_in[0];   // (4,8192,3)
  const float* feat = (const float*)d_in[1];   // (4,64,8192)
  const float* w1   = (const float*)d_in[2];   // (128,67)
  const float* b1   = (const float*)d_in[3];   // (128)
  const float* w2   = (const float*)d_in[4];   // (256,128)
  const float* b2   = (const float*)d_in[5];   // (256)

  float* out     = (float*)d_out;
  float* new_xyz = out;                        // (4,2048,3)
  float* pooled  = out + (size_t)BATCH * NPT * 3;  // (4,256,2048)

  char* ws = (char*)d_ws;
  float*  w1t    = (float*)ws;                         // 34304 B
  float*  w2t    = (float*)(ws + 34304);               // 131072 B
  int*    idx    = (int*)(ws + 34304 + 131072);        // 1048576 B
  float4* sorted = (float4*)(ws + 34304 + 131072 + 1048576);  // 524288 B (16B-aligned)

  prep_kernel<<<128, 256, 0, stream>>>(w1, w2, w1t, w2t);
  sort_kernel<<<BATCH, 1024, 0, stream>>>(xyz, sorted);
  fps_kernel<<<BATCH, 512, 0, stream>>>(xyz, sorted, new_xyz);
  ballquery_kernel<<<(BATCH * NPT) / 4, 256, 0, stream>>>(xyz, new_xyz, idx);
  group_mlp_kernel<<<BATCH * NPT, 256, 0, stream>>>(xyz, feat, new_xyz, idx,
                                                    w1t, b1, w2t, b2, pooled);
}

// Round 9
// 2133.495 us; speedup vs baseline: 2.0343x; 2.0343x over previous
//
#include <hip/hip_runtime.h>

// Problem constants (from reference)
#define NPTS   8192   // N
#define NPT    2048   // NPOINT
#define NS     32     // NSAMPLE
#define CIN    64
#define BATCH  4
// threshold: f32 nearest to 0.64 (numpy/jax weak-type the python float 0.8**2 to f32)
#define R2     0.64f

// ---------------- prep: transpose weights into ws ----------------
__global__ __launch_bounds__(256) void prep_kernel(const float* __restrict__ w1,
                                                   const float* __restrict__ w2,
                                                   float* __restrict__ w1t,
                                                   float* __restrict__ w2t) {
  int i = blockIdx.x * 256 + threadIdx.x;
  if (i < 128 * 67) {
    int o = i / 67, c = i % 67;
    w1t[c * 128 + o] = w1[i];
  }
  if (i < 256 * 128) {
    int o = i >> 7, c = i & 127;
    w2t[c * 256 + o] = w2[i];
  }
}

// ---------------- Morton sort (u32 keys, in-LDS bitonic) ----------------
__device__ inline uint32_t part1by2(uint32_t x) {
  x &= 1023u;
  x = (x | (x << 16)) & 0x030000FFu;
  x = (x | (x << 8))  & 0x0300F00Fu;
  x = (x | (x << 4))  & 0x030C30C3u;
  x = (x | (x << 2))  & 0x09249249u;
  return x;
}

__device__ inline uint32_t morton3(float x, float y, float z) {
  int qx = (int)((x + 16.f) * 32.f);
  int qy = (int)((y + 16.f) * 32.f);
  int qz = (int)((z + 16.f) * 32.f);
  qx = qx < 0 ? 0 : (qx > 1023 ? 1023 : qx);
  qy = qy < 0 ? 0 : (qy > 1023 ? 1023 : qy);
  qz = qz < 0 ? 0 : (qz > 1023 ? 1023 : qz);
  return part1by2((uint32_t)qx) | (part1by2((uint32_t)qy) << 1) | (part1by2((uint32_t)qz) << 2);
}

// key = (morton top 19 bits << 13) | idx. Sort order only affects clustering
// quality, never correctness (min-updates are exact & order-independent).
__global__ __launch_bounds__(1024) void sort_kernel(const float* __restrict__ xyz,
                                                    float4* __restrict__ sorted) {
  const int b = blockIdx.x;
  const int tid = threadIdx.x;
  const float* X = xyz + (size_t)b * NPTS * 3;
  __shared__ uint32_t S[NPTS];  // 32 KB

  for (int k = 0; k < 8; ++k) {
    int p = tid + (k << 10);
    uint32_t m = morton3(X[p * 3 + 0], X[p * 3 + 1], X[p * 3 + 2]);
    S[p] = ((m >> 11) << 13) | (uint32_t)p;
  }
  __syncthreads();
  for (unsigned k = 2; k <= NPTS; k <<= 1) {
    for (unsigned j = k >> 1; j > 0; j >>= 1) {
      for (int i = tid; i < NPTS; i += 1024) {
        int l = i ^ (int)j;
        if (l > i) {
          uint32_t a = S[i], c = S[l];
          bool sw = ((i & k) == 0) ? (a > c) : (a < c);
          if (sw) { S[i] = c; S[l] = a; }
        }
      }
      __syncthreads();
    }
  }
  for (int k = 0; k < 8; ++k) {
    int pos = tid + (k << 10);
    int o = (int)(S[pos] & 8191u);
    float4 v;
    v.x = X[o * 3 + 0]; v.y = X[o * 3 + 1]; v.z = X[o * 3 + 2];
    v.w = __int_as_float(o);
    sorted[(size_t)b * NPTS + pos] = v;
  }
}

// ---------------- FPS v9: R7 structure (regs, 1024x8, cached wave-reduce,
//                  LDS coord table) + leader-wave block stage + LDS bcast +
//                  LDS-buffered new_xyz ----------------
// Bit-exactness (verified absmax 0.0 in R2/R3/R6/R7 with identical math):
//  * min-updates use exact-rounded ((dx*dx+dy*dy)+dz*dz); order-independent.
//  * cluster skipped only if 0.9999-scaled conservative bbox lower bound
//    >= cluster max dmin -> skip provably a no-op (1e-4 margin >> 2e-7 rounding).
//  * cached wave (wwm,wwi) reused only when NO lane of the wave burst ->
//    nothing changed -> identical reduction result. Winner's cluster
//    self-activates next iter (center in bbox -> dlb=0); cmaxv==0 clusters
//    are immutable so their skip is safe.
//  * all dists nonneg f32, so u32 order == float order.
//  * tie-breaks -> smallest original index at every stage (numpy argmax).
// Race-freedom of the 2-barrier broadcast: writes to rec[buf]/bcast[buf]
// happen strictly between barrier2(t-1) and barrier1(t) / barrier1(t) and
// barrier2(t); all reads of buf-slots complete before the next write to the
// same slot (ping-pong on t&1, two barriers per iteration).

#define DPP_ROR_U32_MAX(v)                                                       \
  {                                                                              \
    uint32_t _t;                                                                 \
    _t = (uint32_t)__builtin_amdgcn_update_dpp(0, (int)(v), 0x121, 0xF, 0xF, false); if (_t > (v)) (v) = _t; \
    _t = (uint32_t)__builtin_amdgcn_update_dpp(0, (int)(v), 0x122, 0xF, 0xF, false); if (_t > (v)) (v) = _t; \
    _t = (uint32_t)__builtin_amdgcn_update_dpp(0, (int)(v), 0x124, 0xF, 0xF, false); if (_t > (v)) (v) = _t; \
    _t = (uint32_t)__builtin_amdgcn_update_dpp(0, (int)(v), 0x128, 0xF, 0xF, false); if (_t > (v)) (v) = _t; \
  }

#define DPP_ROR_U32_MIN(v)                                                       \
  {                                                                              \
    uint32_t _t;                                                                 \
    _t = (uint32_t)__builtin_amdgcn_update_dpp(-1, (int)(v), 0x121, 0xF, 0xF, false); if (_t < (v)) (v) = _t; \
    _t = (uint32_t)__builtin_amdgcn_update_dpp(-1, (int)(v), 0x122, 0xF, 0xF, false); if (_t < (v)) (v) = _t; \
    _t = (uint32_t)__builtin_amdgcn_update_dpp(-1, (int)(v), 0x124, 0xF, 0xF, false); if (_t < (v)) (v) = _t; \
    _t = (uint32_t)__builtin_amdgcn_update_dpp(-1, (int)(v), 0x128, 0xF, 0xF, false); if (_t < (v)) (v) = _t; \
  }

#define CSWAP(i, j)                                                              \
  if (oid[i] > oid[j]) {                                                         \
    int _ti = oid[i]; oid[i] = oid[j]; oid[j] = _ti;                             \
    float _tf;                                                                   \
    _tf = px[i]; px[i] = px[j]; px[j] = _tf;                                     \
    _tf = py[i]; py[i] = py[j]; py[j] = _tf;                                     \
    _tf = pz[i]; pz[i] = pz[j]; pz[j] = _tf;                                     \
  }

__global__ __launch_bounds__(1024) void fps_kernel(const float* __restrict__ xyz,
                                                   const float4* __restrict__ sorted,
                                                   float* __restrict__ new_xyz) {
  const int b = blockIdx.x;
  const int tid = threadIdx.x;     // 0..1023
  const int lane = tid & 63;
  const int wv = tid >> 6;         // 0..15
  const float* X = xyz + (size_t)b * NPTS * 3;
  const float4* SP = sorted + (size_t)b * NPTS;

  __shared__ float XL[NPTS * 3];            // 96 KB coord table (orig-index order)
  __shared__ float NXL[NPT * 3];            // 24 KB result buffer
  __shared__ __align__(8) uint2  rec[2][16];
  __shared__ __align__(16) float4 bcast[2];

  // stage coords into LDS (coalesced; read-only in the loop)
  for (int i = tid; i < NPTS * 3; i += 1024) XL[i] = X[i];

  // own 8 CONTIGUOUS morton-sorted points (one spatial cluster per thread)
  float px[8], py[8], pz[8], dmin[8];
  int oid[8];
#pragma unroll
  for (int k = 0; k < 8; ++k) {
    float4 p = SP[tid * 8 + k];
    px[k] = p.x; py[k] = p.y; pz[k] = p.z;
    oid[k] = __float_as_int(p.w);
    dmin[k] = 1e10f;
  }
  // sort the 8 points by original index (Batcher 19-comparator network) so the
  // burst argmax tie-break is a strict '>' (first max == smallest oid).
  CSWAP(0, 1) CSWAP(2, 3) CSWAP(4, 5) CSWAP(6, 7)
  CSWAP(0, 2) CSWAP(1, 3) CSWAP(4, 6) CSWAP(5, 7)
  CSWAP(1, 2) CSWAP(5, 6)
  CSWAP(0, 4) CSWAP(1, 5) CSWAP(2, 6) CSWAP(3, 7)
  CSWAP(2, 4) CSWAP(3, 5)
  CSWAP(1, 2) CSWAP(3, 4) CSWAP(5, 6)

  // cluster bbox
  float bxmin = px[0], bxmax = px[0], bymin = py[0], bymax = py[0], bzmin = pz[0], bzmax = pz[0];
#pragma unroll
  for (int k = 1; k < 8; ++k) {
    bxmin = fminf(bxmin, px[k]); bxmax = fmaxf(bxmax, px[k]);
    bymin = fminf(bymin, py[k]); bymax = fmaxf(bymax, py[k]);
    bzmin = fminf(bzmin, pz[k]); bzmax = fmaxf(bzmax, pz[k]);
  }
  float cmaxv = 1e10f;   // forces full update at t=1 (dlb << 1e10)
  int   cmaxi = oid[0];

  // cached wave-winner (valid after first iteration; t=1 always recomputes)
  uint32_t wwm = 0u, wwi = 0u;

  float cx = X[0], cy = X[1], cz = X[2];
  if (tid == 0) { NXL[0] = cx; NXL[1] = cy; NXL[2] = cz; }
  __syncthreads();   // XL (and NXL[0..2]) ready

  for (int t = 1; t < NPT; ++t) {
    // conservative lower bound of squared dist from center to cluster bbox
    float ex = fmaxf(fmaxf(bxmin - cx, cx - bxmax), 0.f);
    float ey = fmaxf(fmaxf(bymin - cy, cy - bymax), 0.f);
    float ez = fmaxf(fmaxf(bzmin - cz, cz - bzmax), 0.f);
    float dlb = (ex * ex + ey * ey + ez * ez) * 0.9999f;
    bool act = dlb < cmaxv;

    if (__ballot(act)) {           // wave-uniform: any lane needs a burst?
      if (act) {
        float mv = -1.0f; int mi = 0;
#pragma unroll
        for (int k = 0; k < 8; ++k) {
          float dx = px[k] - cx, dy = py[k] - cy, dz = pz[k] - cz;
          float d = __fadd_rn(__fadd_rn(__fmul_rn(dx, dx), __fmul_rn(dy, dy)), __fmul_rn(dz, dz));
          float dm = fminf(dmin[k], d);
          dmin[k] = dm;
          if (dm > mv) { mv = dm; mi = oid[k]; }   // strict > : first max = min oid
        }
        cmaxv = mv; cmaxi = mi;
      }
      // ---- wave reduction (recomputed only when something changed) ----
      uint32_t vb = __float_as_uint(cmaxv);
      uint32_t rm = vb;
      DPP_ROR_U32_MAX(rm)   // every lane: max of its 16-lane row
      uint32_t m0 = (uint32_t)__builtin_amdgcn_readlane((int)rm, 0);
      uint32_t m1 = (uint32_t)__builtin_amdgcn_readlane((int)rm, 16);
      uint32_t m2 = (uint32_t)__builtin_amdgcn_readlane((int)rm, 32);
      uint32_t m3 = (uint32_t)__builtin_amdgcn_readlane((int)rm, 48);
      uint32_t wm = m0 > m1 ? m0 : m1;
      uint32_t wmb = m2 > m3 ? m2 : m3;
      wm = wm > wmb ? wm : wmb;
      // index stage: ballot fast path (unique max), exact DPP-min fallback
      unsigned long long em = __ballot(vb == wm);
      uint32_t wi;
      if (__popcll(em) == 1) {
        wi = (uint32_t)__builtin_amdgcn_readlane(cmaxi, __ffsll(em) - 1);
      } else {
        uint32_t ik = (vb == wm) ? (uint32_t)cmaxi : 0xFFFFFFFFu;
        DPP_ROR_U32_MIN(ik)
        uint32_t i0 = (uint32_t)__builtin_amdgcn_readlane((int)ik, 0);
        uint32_t i1 = (uint32_t)__builtin_amdgcn_readlane((int)ik, 16);
        uint32_t i2 = (uint32_t)__builtin_amdgcn_readlane((int)ik, 32);
        uint32_t i3 = (uint32_t)__builtin_amdgcn_readlane((int)ik, 48);
        wi = i0 < i1 ? i0 : i1;
        uint32_t wib = i2 < i3 ? i2 : i3;
        wi = wi < wib ? wi : wib;
      }
      wwm = wm; wwi = wi;
    }

    const int buf = t & 1;
    if (lane == 0) { rec[buf][wv].x = wwm; rec[buf][wv].y = wwi; }
    __syncthreads();   // barrier 1: rec ready

    // ---- leader wave only: block stage + winner coords + broadcast ----
    if (wv == 0) {
      uint2 r = rec[buf][lane & 15];
      uint32_t bm = r.x;
      DPP_ROR_U32_MAX(bm)                        // block max (rows replicate)
      uint32_t ci = (r.x == bm) ? r.y : 0xFFFFFFFFu;
      DPP_ROR_U32_MIN(ci)                        // min idx among matching waves
      int sidx = __builtin_amdgcn_readfirstlane((int)ci);
      float nx = XL[3 * sidx + 0];               // uniform LDS broadcast reads
      float ny = XL[3 * sidx + 1];
      float nz = XL[3 * sidx + 2];
      if (lane == 0) {
        bcast[buf] = make_float4(nx, ny, nz, 0.f);
        float* o = NXL + 3 * t;
        o[0] = nx; o[1] = ny; o[2] = nz;
      }
    }
    __syncthreads();   // barrier 2: bcast ready

    float4 c4 = bcast[buf];
    cx = c4.x; cy = c4.y; cz = c4.z;
  }

  // flush result buffer (all NXL writes precede the final barrier 2)
  for (int i = tid; i < NPT * 3; i += 1024)
    new_xyz[(size_t)b * NPT * 3 + i] = NXL[i];
}

// ---------------- ball query: one wave per (b,s) ----------------
__global__ __launch_bounds__(256) void ballquery_kernel(const float* __restrict__ xyz,
                                                        const float* __restrict__ new_xyz,
                                                        int* __restrict__ idx_out) {
  const int w = blockIdx.x * 4 + (threadIdx.x >> 6);   // (b*2048 + s)
  const int lane = threadIdx.x & 63;
  const int b = w >> 11;
  const float* X = xyz + (size_t)b * NPTS * 3;
  const float cx = new_xyz[w * 3 + 0];
  const float cy = new_xyz[w * 3 + 1];
  const float cz = new_xyz[w * 3 + 2];
  int* out = idx_out + (size_t)w * NS;

  int found = 0;
  int first = -1;
  for (int base = 0; base < NPTS; base += 64) {
    const int p = base + lane;
    float x = X[p * 3 + 0], y = X[p * 3 + 1], z = X[p * 3 + 2];
    float dx = x - cx, dy = y - cy, dz = z - cz;
    float d2 = __fadd_rn(__fadd_rn(__fmul_rn(dx, dx), __fmul_rn(dy, dy)), __fmul_rn(dz, dz));
    unsigned long long mask = __ballot(d2 < R2);
    if (mask != 0ull && first < 0) first = base + __ffsll((unsigned long long)mask) - 1;
    if (found < NS) {
      if ((mask >> lane) & 1ull) {
        int rank = found + __popcll(mask & ((1ull << lane) - 1ull));
        if (rank < NS) out[rank] = p;
      }
    }
    found += __popcll(mask);
    if (found >= NS) break;
  }
  if (found < NS) {
    int pad = (first < 0) ? 0 : first;
    if (lane >= found && lane < NS) out[lane] = pad;
  }
}

// ---------------- group + MLP(67->128->256) + maxpool: one block per (b,s) ----------------
__global__ __launch_bounds__(256) void group_mlp_kernel(const float* __restrict__ xyz,
                                                        const float* __restrict__ feat,
                                                        const float* __restrict__ new_xyz,
                                                        const int* __restrict__ idx,
                                                        const float* __restrict__ w1t,
                                                        const float* __restrict__ b1,
                                                        const float* __restrict__ w2t,
                                                        const float* __restrict__ b2,
                                                        float* __restrict__ pooled) {
  const int blk = blockIdx.x;       // b*2048 + s
  const int b = blk >> 11, s = blk & 2047;
  const int tid = threadIdx.x;

  __shared__ __align__(16) float G[67 * 32];    // (C+3) x ns
  __shared__ __align__(16) float H1[128 * 32];  // 128 x ns
  __shared__ int   lidx[NS];
  __shared__ float ctr[3];

  if (tid < NS) lidx[tid] = idx[(size_t)blk * NS + tid];
  if (tid < 3)  ctr[tid] = new_xyz[blk * 3 + tid];
  __syncthreads();

  const float* F = feat + (size_t)b * CIN * NPTS;
  const float* X = xyz + (size_t)b * NPTS * 3;

  for (int e = tid; e < 67 * 32; e += 256) {
    int c = e >> 5, j = e & 31;
    int p = lidx[j];
    float v;
    if (c < 3) v = X[p * 3 + c] - ctr[c];
    else       v = F[(size_t)(c - 3) * NPTS + p];
    G[e] = v;
  }
  __syncthreads();

  // H1 = relu(W1 @ G + b1): 128x32, each thread 4o x 4j
  {
    const int oi = tid >> 3, ji = tid & 7;
    const int o0 = oi * 4, j0 = ji * 4;
    float acc[4][4];
#pragma unroll
    for (int i = 0; i < 4; ++i)
#pragma unroll
      for (int jj = 0; jj < 4; ++jj) acc[i][jj] = 0.f;
#pragma unroll 4
    for (int c = 0; c < 67; ++c) {
      float4 g  = *(const float4*)&G[c * 32 + j0];
      float4 wf = *(const float4*)&w1t[c * 128 + o0];
      float ga[4] = {g.x, g.y, g.z, g.w};
      float wa[4] = {wf.x, wf.y, wf.z, wf.w};
#pragma unroll
      for (int i = 0; i < 4; ++i)
#pragma unroll
        for (int jj = 0; jj < 4; ++jj)
          acc[i][jj] = fmaf(wa[i], ga[jj], acc[i][jj]);
    }
    float4 bb = *(const float4*)&b1[o0];
    float ba[4] = {bb.x, bb.y, bb.z, bb.w};
#pragma unroll
    for (int i = 0; i < 4; ++i) {
      float4 h;
      h.x = fmaxf(acc[i][0] + ba[i], 0.f);
      h.y = fmaxf(acc[i][1] + ba[i], 0.f);
      h.z = fmaxf(acc[i][2] + ba[i], 0.f);
      h.w = fmaxf(acc[i][3] + ba[i], 0.f);
      *(float4*)&H1[(o0 + i) * 32 + j0] = h;
    }
  }
  __syncthreads();

  // H2 = relu(W2 @ H1 + b2): 256x32, each thread 8o x 4j, then maxpool over j
  {
    const int oi = tid >> 3, ji = tid & 7;
    const int o0 = oi * 8, j0 = ji * 4;
    float acc[8][4];
#pragma unroll
    for (int i = 0; i < 8; ++i)
#pragma unroll
      for (int jj = 0; jj < 4; ++jj) acc[i][jj] = 0.f;
#pragma unroll 2
    for (int c = 0; c < 128; ++c) {
      float4 h  = *(const float4*)&H1[c * 32 + j0];
      float4 wa4 = *(const float4*)&w2t[c * 256 + o0];
      float4 wb4 = *(const float4*)&w2t[c * 256 + o0 + 4];
      float ha[4] = {h.x, h.y, h.z, h.w};
      float wa[8] = {wa4.x, wa4.y, wa4.z, wa4.w, wb4.x, wb4.y, wb4.z, wb4.w};
#pragma unroll
      for (int i = 0; i < 8; ++i)
#pragma unroll
        for (int jj = 0; jj < 4; ++jj)
          acc[i][jj] = fmaf(wa[i], ha[jj], acc[i][jj]);
    }
    float4 b2a = *(const float4*)&b2[o0];
    float4 b2b = *(const float4*)&b2[o0 + 4];
    float bb[8] = {b2a.x, b2a.y, b2a.z, b2a.w, b2b.x, b2b.y, b2b.z, b2b.w};
    float m[8];
#pragma unroll
    for (int i = 0; i < 8; ++i) {
      float v0 = fmaxf(acc[i][0] + bb[i], 0.f);
      float v1 = fmaxf(acc[i][1] + bb[i], 0.f);
      float v2 = fmaxf(acc[i][2] + bb[i], 0.f);
      float v3 = fmaxf(acc[i][3] + bb[i], 0.f);
      m[i] = fmaxf(fmaxf(v0, v1), fmaxf(v2, v3));
    }
#pragma unroll
    for (int off = 1; off < 8; off <<= 1)
#pragma unroll
      for (int i = 0; i < 8; ++i) m[i] = fmaxf(m[i], __shfl_xor(m[i], off));
    if (ji == 0) {
#pragma unroll
      for (int i = 0; i < 8; ++i)
        pooled[((size_t)b * 256 + o0 + i) * (size_t)NPT + s] = m[i];
    }
  }
}

extern "C" void kernel_launch(void* const* d_in, const int* in_sizes, int n_in,
                              void* d_out, int out_size, void* d_ws, size_t ws_size,
                              hipStream_t stream) {
  (void)in_sizes; (void)n_in; (void)out_size; (void)ws_size;
  const float* xyz  = (const float*)d_in[0];   // (4,8192,3)
  const float* feat = (const float*)d_in[1];   // (4,64,8192)
  const float* w1   = (const float*)d_in[2];   // (128,67)
  const float* b1   = (const float*)d_in[3];   // (128)
  const float* w2   = (const float*)d_in[4];   // (256,128)
  const float* b2   = (const float*)d_in[5];   // (256)

  float* out     = (float*)d_out;
  float* new_xyz = out;                        // (4,2048,3)
  float* pooled  = out + (size_t)BATCH * NPT * 3;  // (4,256,2048)

  char* ws = (char*)d_ws;
  float*  w1t    = (float*)ws;                         // 34304 B
  float*  w2t    = (float*)(ws + 34304);               // 131072 B
  int*    idx    = (int*)(ws + 34304 + 131072);        // 1048576 B
  float4* sorted = (float4*)(ws + 34304 + 131072 + 1048576);  // 524288 B (16B-aligned)

  prep_kernel<<<128, 256, 0, stream>>>(w1, w2, w1t, w2t);
  sort_kernel<<<BATCH, 1024, 0, stream>>>(xyz, sorted);
  fps_kernel<<<BATCH, 1024, 0, stream>>>(xyz, sorted, new_xyz);
  ballquery_kernel<<<(BATCH * NPT) / 4, 256, 0, stream>>>(xyz, new_xyz, idx);
  group_mlp_kernel<<<BATCH * NPT, 256, 0, stream>>>(xyz, feat, new_xyz, idx,
                                                    w1t, b1, w2t, b2, pooled);
}

// Round 10
// 1927.120 us; speedup vs baseline: 2.2521x; 1.1071x over previous
//
#include <hip/hip_runtime.h>

// Problem constants (from reference)
#define NPTS   8192   // N
#define NPT    2048   // NPOINT
#define NS     32     // NSAMPLE
#define CIN    64
#define BATCH  4
// threshold: f32 nearest to 0.64 (numpy/jax weak-type the python float 0.8**2 to f32)
#define R2     0.64f

// ---------------- prep: transpose weights into ws ----------------
__global__ __launch_bounds__(256) void prep_kernel(const float* __restrict__ w1,
                                                   const float* __restrict__ w2,
                                                   float* __restrict__ w1t,
                                                   float* __restrict__ w2t) {
  int i = blockIdx.x * 256 + threadIdx.x;
  if (i < 128 * 67) {
    int o = i / 67, c = i % 67;
    w1t[c * 128 + o] = w1[i];
  }
  if (i < 256 * 128) {
    int o = i >> 7, c = i & 127;
    w2t[c * 256 + o] = w2[i];
  }
}

// ---------------- Morton sort (u32 keys, in-LDS bitonic) ----------------
__device__ inline uint32_t part1by2(uint32_t x) {
  x &= 1023u;
  x = (x | (x << 16)) & 0x030000FFu;
  x = (x | (x << 8))  & 0x0300F00Fu;
  x = (x | (x << 4))  & 0x030C30C3u;
  x = (x | (x << 2))  & 0x09249249u;
  return x;
}

__device__ inline uint32_t morton3(float x, float y, float z) {
  int qx = (int)((x + 16.f) * 32.f);
  int qy = (int)((y + 16.f) * 32.f);
  int qz = (int)((z + 16.f) * 32.f);
  qx = qx < 0 ? 0 : (qx > 1023 ? 1023 : qx);
  qy = qy < 0 ? 0 : (qy > 1023 ? 1023 : qy);
  qz = qz < 0 ? 0 : (qz > 1023 ? 1023 : qz);
  return part1by2((uint32_t)qx) | (part1by2((uint32_t)qy) << 1) | (part1by2((uint32_t)qz) << 2);
}

// key = (morton top 19 bits << 13) | idx. Sort order only affects clustering
// quality, never correctness (min-updates are exact & order-independent).
__global__ __launch_bounds__(1024) void sort_kernel(const float* __restrict__ xyz,
                                                    float4* __restrict__ sorted) {
  const int b = blockIdx.x;
  const int tid = threadIdx.x;
  const float* X = xyz + (size_t)b * NPTS * 3;
  __shared__ uint32_t S[NPTS];  // 32 KB

  for (int k = 0; k < 8; ++k) {
    int p = tid + (k << 10);
    uint32_t m = morton3(X[p * 3 + 0], X[p * 3 + 1], X[p * 3 + 2]);
    S[p] = ((m >> 11) << 13) | (uint32_t)p;
  }
  __syncthreads();
  for (unsigned k = 2; k <= NPTS; k <<= 1) {
    for (unsigned j = k >> 1; j > 0; j >>= 1) {
      for (int i = tid; i < NPTS; i += 1024) {
        int l = i ^ (int)j;
        if (l > i) {
          uint32_t a = S[i], c = S[l];
          bool sw = ((i & k) == 0) ? (a > c) : (a < c);
          if (sw) { S[i] = c; S[l] = a; }
        }
      }
      __syncthreads();
    }
  }
  for (int k = 0; k < 8; ++k) {
    int pos = tid + (k << 10);
    int o = (int)(S[pos] & 8191u);
    float4 v;
    v.x = X[o * 3 + 0]; v.y = X[o * 3 + 1]; v.z = X[o * 3 + 2];
    v.w = __int_as_float(o);
    sorted[(size_t)b * NPTS + pos] = v;
  }
}

// ---------------- FPS v7 (EXACT R7 revert — verified 1327 us, absmax 0.0) ----
// R9 lesson: redundant parallel block-stage on all waves after ONE barrier
// beats a serialized leader stage between TWO barriers.
// Bit-exactness (verified absmax 0.0 in R2/R3/R6/R7):
//  * min-updates use exact-rounded ((dx*dx+dy*dy)+dz*dz); order-independent.
//  * cluster skipped only if 0.9999-scaled conservative bbox lower bound
//    >= cluster max dmin -> skip provably a no-op.
//  * cached wave (wm,wi) reused only when NO lane of the wave burst.
//  * all dists nonneg f32, so u32 order == float order.
//  * tie-breaks -> smallest original index at every stage (numpy argmax).

#define DPP_ROR_U32_MAX(v)                                                       \
  {                                                                              \
    uint32_t _t;                                                                 \
    _t = (uint32_t)__builtin_amdgcn_update_dpp(0, (int)(v), 0x121, 0xF, 0xF, false); if (_t > (v)) (v) = _t; \
    _t = (uint32_t)__builtin_amdgcn_update_dpp(0, (int)(v), 0x122, 0xF, 0xF, false); if (_t > (v)) (v) = _t; \
    _t = (uint32_t)__builtin_amdgcn_update_dpp(0, (int)(v), 0x124, 0xF, 0xF, false); if (_t > (v)) (v) = _t; \
    _t = (uint32_t)__builtin_amdgcn_update_dpp(0, (int)(v), 0x128, 0xF, 0xF, false); if (_t > (v)) (v) = _t; \
  }

#define DPP_ROR_U32_MIN(v)                                                       \
  {                                                                              \
    uint32_t _t;                                                                 \
    _t = (uint32_t)__builtin_amdgcn_update_dpp(-1, (int)(v), 0x121, 0xF, 0xF, false); if (_t < (v)) (v) = _t; \
    _t = (uint32_t)__builtin_amdgcn_update_dpp(-1, (int)(v), 0x122, 0xF, 0xF, false); if (_t < (v)) (v) = _t; \
    _t = (uint32_t)__builtin_amdgcn_update_dpp(-1, (int)(v), 0x124, 0xF, 0xF, false); if (_t < (v)) (v) = _t; \
    _t = (uint32_t)__builtin_amdgcn_update_dpp(-1, (int)(v), 0x128, 0xF, 0xF, false); if (_t < (v)) (v) = _t; \
  }

#define CSWAP(i, j)                                                              \
  if (oid[i] > oid[j]) {                                                         \
    int _ti = oid[i]; oid[i] = oid[j]; oid[j] = _ti;                             \
    float _tf;                                                                   \
    _tf = px[i]; px[i] = px[j]; px[j] = _tf;                                     \
    _tf = py[i]; py[i] = py[j]; py[j] = _tf;                                     \
    _tf = pz[i]; pz[i] = pz[j]; pz[j] = _tf;                                     \
  }

__global__ __launch_bounds__(1024) void fps_kernel(const float* __restrict__ xyz,
                                                   const float4* __restrict__ sorted,
                                                   float* __restrict__ new_xyz) {
  const int b = blockIdx.x;
  const int tid = threadIdx.x;     // 0..1023
  const int lane = tid & 63;
  const int wv = tid >> 6;         // 0..15
  const float* X = xyz + (size_t)b * NPTS * 3;
  const float4* SP = sorted + (size_t)b * NPTS;

  __shared__ float XL[NPTS * 3];          // 96 KB coord table (winner lookup)
  __shared__ __align__(8) uint2 rec[2][16];

  for (int i = tid; i < NPTS * 3; i += 1024) XL[i] = X[i];

  float px[8], py[8], pz[8], dmin[8];
  int oid[8];
#pragma unroll
  for (int k = 0; k < 8; ++k) {
    float4 p = SP[tid * 8 + k];
    px[k] = p.x; py[k] = p.y; pz[k] = p.z;
    oid[k] = __float_as_int(p.w);
    dmin[k] = 1e10f;
  }
  CSWAP(0, 1) CSWAP(2, 3) CSWAP(4, 5) CSWAP(6, 7)
  CSWAP(0, 2) CSWAP(1, 3) CSWAP(4, 6) CSWAP(5, 7)
  CSWAP(1, 2) CSWAP(5, 6)
  CSWAP(0, 4) CSWAP(1, 5) CSWAP(2, 6) CSWAP(3, 7)
  CSWAP(2, 4) CSWAP(3, 5)
  CSWAP(1, 2) CSWAP(3, 4) CSWAP(5, 6)

  float bxmin = px[0], bxmax = px[0], bymin = py[0], bymax = py[0], bzmin = pz[0], bzmax = pz[0];
#pragma unroll
  for (int k = 1; k < 8; ++k) {
    bxmin = fminf(bxmin, px[k]); bxmax = fmaxf(bxmax, px[k]);
    bymin = fminf(bymin, py[k]); bymax = fmaxf(bymax, py[k]);
    bzmin = fminf(bzmin, pz[k]); bzmax = fmaxf(bzmax, pz[k]);
  }
  float cmaxv = 1e10f;
  int   cmaxi = oid[0];
  uint32_t wwm = 0u, wwi = 0u;

  float cx = X[0], cy = X[1], cz = X[2];
  if (tid == 0) {
    new_xyz[(size_t)b * NPT * 3 + 0] = cx;
    new_xyz[(size_t)b * NPT * 3 + 1] = cy;
    new_xyz[(size_t)b * NPT * 3 + 2] = cz;
  }
  __syncthreads();   // XL ready

  for (int t = 1; t < NPT; ++t) {
    float ex = fmaxf(fmaxf(bxmin - cx, cx - bxmax), 0.f);
    float ey = fmaxf(fmaxf(bymin - cy, cy - bymax), 0.f);
    float ez = fmaxf(fmaxf(bzmin - cz, cz - bzmax), 0.f);
    float dlb = (ex * ex + ey * ey + ez * ez) * 0.9999f;
    bool act = dlb < cmaxv;

    if (__ballot(act)) {
      if (act) {
        float mv = -1.0f; int mi = 0;
#pragma unroll
        for (int k = 0; k < 8; ++k) {
          float dx = px[k] - cx, dy = py[k] - cy, dz = pz[k] - cz;
          float d = __fadd_rn(__fadd_rn(__fmul_rn(dx, dx), __fmul_rn(dy, dy)), __fmul_rn(dz, dz));
          float dm = fminf(dmin[k], d);
          dmin[k] = dm;
          if (dm > mv) { mv = dm; mi = oid[k]; }
        }
        cmaxv = mv; cmaxi = mi;
      }
      uint32_t vb = __float_as_uint(cmaxv);
      uint32_t rm = vb;
      DPP_ROR_U32_MAX(rm)
      uint32_t m0 = (uint32_t)__builtin_amdgcn_readlane((int)rm, 0);
      uint32_t m1 = (uint32_t)__builtin_amdgcn_readlane((int)rm, 16);
      uint32_t m2 = (uint32_t)__builtin_amdgcn_readlane((int)rm, 32);
      uint32_t m3 = (uint32_t)__builtin_amdgcn_readlane((int)rm, 48);
      uint32_t wm = m0 > m1 ? m0 : m1;
      uint32_t wmb = m2 > m3 ? m2 : m3;
      wm = wm > wmb ? wm : wmb;
      unsigned long long em = __ballot(vb == wm);
      uint32_t wi;
      if (__popcll(em) == 1) {
        wi = (uint32_t)__builtin_amdgcn_readlane(cmaxi, __ffsll(em) - 1);
      } else {
        uint32_t ik = (vb == wm) ? (uint32_t)cmaxi : 0xFFFFFFFFu;
        DPP_ROR_U32_MIN(ik)
        uint32_t i0 = (uint32_t)__builtin_amdgcn_readlane((int)ik, 0);
        uint32_t i1 = (uint32_t)__builtin_amdgcn_readlane((int)ik, 16);
        uint32_t i2 = (uint32_t)__builtin_amdgcn_readlane((int)ik, 32);
        uint32_t i3 = (uint32_t)__builtin_amdgcn_readlane((int)ik, 48);
        wi = i0 < i1 ? i0 : i1;
        uint32_t wib = i2 < i3 ? i2 : i3;
        wi = wi < wib ? wi : wib;
      }
      wwm = wm; wwi = wi;
    }

    const int buf = t & 1;
    if (lane == 0) { rec[buf][wv].x = wwm; rec[buf][wv].y = wwi; }
    __syncthreads();

    uint2 r = rec[buf][lane & 15];
    uint32_t bm = r.x;
    DPP_ROR_U32_MAX(bm)
    uint32_t ci = (r.x == bm) ? r.y : 0xFFFFFFFFu;
    DPP_ROR_U32_MIN(ci)
    int sidx = __builtin_amdgcn_readfirstlane((int)ci);

    cx = XL[3 * sidx + 0];
    cy = XL[3 * sidx + 1];
    cz = XL[3 * sidx + 2];

    if (tid == 0) {
      float* o = new_xyz + ((size_t)b * NPT + t) * 3;
      o[0] = cx; o[1] = cy; o[2] = cz;
    }
  }
}

// ---------------- ball query: one wave per (b,s) ----------------
__global__ __launch_bounds__(256) void ballquery_kernel(const float* __restrict__ xyz,
                                                        const float* __restrict__ new_xyz,
                                                        int* __restrict__ idx_out) {
  const int w = blockIdx.x * 4 + (threadIdx.x >> 6);   // (b*2048 + s)
  const int lane = threadIdx.x & 63;
  const int b = w >> 11;
  const float* X = xyz + (size_t)b * NPTS * 3;
  const float cx = new_xyz[w * 3 + 0];
  const float cy = new_xyz[w * 3 + 1];
  const float cz = new_xyz[w * 3 + 2];
  int* out = idx_out + (size_t)w * NS;

  int found = 0;
  int first = -1;
  for (int base = 0; base < NPTS; base += 64) {
    const int p = base + lane;
    float x = X[p * 3 + 0], y = X[p * 3 + 1], z = X[p * 3 + 2];
    float dx = x - cx, dy = y - cy, dz = z - cz;
    float d2 = __fadd_rn(__fadd_rn(__fmul_rn(dx, dx), __fmul_rn(dy, dy)), __fmul_rn(dz, dz));
    unsigned long long mask = __ballot(d2 < R2);
    if (mask != 0ull && first < 0) first = base + __ffsll((unsigned long long)mask) - 1;
    if (found < NS) {
      if ((mask >> lane) & 1ull) {
        int rank = found + __popcll(mask & ((1ull << lane) - 1ull));
        if (rank < NS) out[rank] = p;
      }
    }
    found += __popcll(mask);
    if (found >= NS) break;
  }
  if (found < NS) {
    int pad = (first < 0) ? 0 : first;
    if (lane >= found && lane < NS) out[lane] = pad;
  }
}

// ---------------- group + MLP + maxpool: 2 centers per 512-thread block ------
// Same math as the verified 1-s kernel; per-thread tile shapes unchanged
// (H1: 4o x 4j, H2: 8o x 4j), so LDS patterns stay conflict-free; block count
// halves (4096), barriers/prologue amortized over 2 centers.
__global__ __launch_bounds__(512) void group_mlp_kernel(const float* __restrict__ xyz,
                                                        const float* __restrict__ feat,
                                                        const float* __restrict__ new_xyz,
                                                        const int* __restrict__ idx,
                                                        const float* __restrict__ w1t,
                                                        const float* __restrict__ b1,
                                                        const float* __restrict__ w2t,
                                                        const float* __restrict__ b2,
                                                        float* __restrict__ pooled) {
  const int blk = blockIdx.x;            // pair id: s-global = 2*blk, 2*blk+1
  const int b = blk >> 10;               // batch (2048 s per batch / 2 per block)
  const int sin0 = (2 * blk) & 2047;     // s within batch for local j<32
  const int tid = threadIdx.x;

  __shared__ __align__(16) float G[67 * 64];    // (C+3) x 64   (17152 B)
  __shared__ __align__(16) float H1[128 * 64];  // 128 x 64     (32768 B)
  __shared__ int   lidx[2 * NS];
  __shared__ float ctr[6];

  if (tid < 64) lidx[tid] = idx[(size_t)(2 * blk) * NS + tid];
  if (tid < 6)  ctr[tid] = new_xyz[(size_t)(2 * blk) * 3 + tid];
  __syncthreads();

  const float* F = feat + (size_t)b * CIN * NPTS;
  const float* X = xyz + (size_t)b * NPTS * 3;

  // fill G: rows 0..2 = rel xyz (per local s), rows 3..66 = gathered features
  for (int e = tid; e < 67 * 64; e += 512) {
    int c = e >> 6, j = e & 63;
    int sl = j >> 5;
    int p = lidx[j];
    float v;
    if (c < 3) v = X[p * 3 + c] - ctr[sl * 3 + c];
    else       v = F[(size_t)(c - 3) * NPTS + p];
    G[e] = v;
  }
  __syncthreads();

  // H1 = relu(W1 @ G + b1): 128 x 64, each thread 4o x 4j
  {
    const int oi = tid >> 4, ji = tid & 15;    // 32 oi x 16 ji
    const int o0 = oi * 4, j0 = ji * 4;
    float acc[4][4];
#pragma unroll
    for (int i = 0; i < 4; ++i)
#pragma unroll
      for (int jj = 0; jj < 4; ++jj) acc[i][jj] = 0.f;
#pragma unroll 4
    for (int c = 0; c < 67; ++c) {
      float4 g  = *(const float4*)&G[c * 64 + j0];
      float4 wf = *(const float4*)&w1t[c * 128 + o0];
      float ga[4] = {g.x, g.y, g.z, g.w};
      float wa[4] = {wf.x, wf.y, wf.z, wf.w};
#pragma unroll
      for (int i = 0; i < 4; ++i)
#pragma unroll
        for (int jj = 0; jj < 4; ++jj)
          acc[i][jj] = fmaf(wa[i], ga[jj], acc[i][jj]);
    }
    float4 bb = *(const float4*)&b1[o0];
    float ba[4] = {bb.x, bb.y, bb.z, bb.w};
#pragma unroll
    for (int i = 0; i < 4; ++i) {
      float4 h;
      h.x = fmaxf(acc[i][0] + ba[i], 0.f);
      h.y = fmaxf(acc[i][1] + ba[i], 0.f);
      h.z = fmaxf(acc[i][2] + ba[i], 0.f);
      h.w = fmaxf(acc[i][3] + ba[i], 0.f);
      *(float4*)&H1[(o0 + i) * 64 + j0] = h;
    }
  }
  __syncthreads();

  // H2 = relu(W2 @ H1 + b2): 256 x 64, each thread 8o x 4j, then maxpool
  {
    const int oi = tid >> 4, ji = tid & 15;    // 32 oi x 16 ji
    const int o0 = oi * 8, j0 = ji * 4;
    float acc[8][4];
#pragma unroll
    for (int i = 0; i < 8; ++i)
#pragma unroll
      for (int jj = 0; jj < 4; ++jj) acc[i][jj] = 0.f;
#pragma unroll 2
    for (int c = 0; c < 128; ++c) {
      float4 h  = *(const float4*)&H1[c * 64 + j0];
      float4 wa4 = *(const float4*)&w2t[c * 256 + o0];
      float4 wb4 = *(const float4*)&w2t[c * 256 + o0 + 4];
      float ha[4] = {h.x, h.y, h.z, h.w};
      float wa[8] = {wa4.x, wa4.y, wa4.z, wa4.w, wb4.x, wb4.y, wb4.z, wb4.w};
#pragma unroll
      for (int i = 0; i < 8; ++i)
#pragma unroll
        for (int jj = 0; jj < 4; ++jj)
          acc[i][jj] = fmaf(wa[i], ha[jj], acc[i][jj]);
    }
    float4 b2a = *(const float4*)&b2[o0];
    float4 b2b = *(const float4*)&b2[o0 + 4];
    float bb[8] = {b2a.x, b2a.y, b2a.z, b2a.w, b2b.x, b2b.y, b2b.z, b2b.w};
    float m[8];
#pragma unroll
    for (int i = 0; i < 8; ++i) {
      float v0 = fmaxf(acc[i][0] + bb[i], 0.f);
      float v1 = fmaxf(acc[i][1] + bb[i], 0.f);
      float v2 = fmaxf(acc[i][2] + bb[i], 0.f);
      float v3 = fmaxf(acc[i][3] + bb[i], 0.f);
      m[i] = fmaxf(fmaxf(v0, v1), fmaxf(v2, v3));
    }
    // lanes in a wave: 4 oi-groups x 16 ji; ji 0..7 -> s0, ji 8..15 -> s1.
    // xor offsets 1,2,4 reduce within each 8-lane half (never cross halves).
#pragma unroll
    for (int off = 1; off < 8; off <<= 1)
#pragma unroll
      for (int i = 0; i < 8; ++i) m[i] = fmaxf(m[i], __shfl_xor(m[i], off));
    const int ji_ = tid & 15;
    if (ji_ == 0 || ji_ == 8) {
      int sidx = sin0 + (ji_ >> 3);
#pragma unroll
      for (int i = 0; i < 8; ++i)
        pooled[((size_t)b * 256 + o0 + i) * (size_t)NPT + sidx] = m[i];
    }
  }
}

extern "C" void kernel_launch(void* const* d_in, const int* in_sizes, int n_in,
                              void* d_out, int out_size, void* d_ws, size_t ws_size,
                              hipStream_t stream) {
  (void)in_sizes; (void)n_in; (void)out_size; (void)ws_size;
  const float* xyz  = (const float*)d_in[0];   // (4,8192,3)
  const float* feat = (const float*)d_in[1];   // (4,64,8192)
  const float* w1   = (const float*)d_in[2];   // (128,67)
  const float* b1   = (const float*)d_in[3];   // (128)
  const float* w2   = (const float*)d_in[4];   // (256,128)
  const float* b2   = (const float*)d_in[5];   // (256)

  float* out     = (float*)d_out;
  float* new_xyz = out;                        // (4,2048,3)
  float* pooled  = out + (size_t)BATCH * NPT * 3;  // (4,256,2048)

  char* ws = (char*)d_ws;
  float*  w1t    = (float*)ws;                         // 34304 B
  float*  w2t    = (float*)(ws + 34304);               // 131072 B
  int*    idx    = (int*)(ws + 34304 + 131072);        // 1048576 B
  float4* sorted = (float4*)(ws + 34304 + 131072 + 1048576);  // 524288 B (16B-aligned)

  prep_kernel<<<128, 256, 0, stream>>>(w1, w2, w1t, w2t);
  sort_kernel<<<BATCH, 1024, 0, stream>>>(xyz, sorted);
  fps_kernel<<<BATCH, 1024, 0, stream>>>(xyz, sorted, new_xyz);
  ballquery_kernel<<<(BATCH * NPT) / 4, 256, 0, stream>>>(xyz, new_xyz, idx);
  group_mlp_kernel<<<(BATCH * NPT) / 2, 512, 0, stream>>>(xyz, feat, new_xyz, idx,
                                                          w1t, b1, w2t, b2, pooled);
}

// Round 11
// 1922.893 us; speedup vs baseline: 2.2571x; 1.0022x over previous
//
#include <hip/hip_runtime.h>

// Problem constants (from reference)
#define NPTS   8192   // N
#define NPT    2048   // NPOINT
#define NS     32     // NSAMPLE
#define CIN    64
#define BATCH  4
// threshold: f32 nearest to 0.64 (numpy/jax weak-type the python float 0.8**2 to f32)
#define R2     0.64f

// ---------------- prep: transpose weights into ws ----------------
__global__ __launch_bounds__(256) void prep_kernel(const float* __restrict__ w1,
                                                   const float* __restrict__ w2,
                                                   float* __restrict__ w1t,
                                                   float* __restrict__ w2t) {
  int i = blockIdx.x * 256 + threadIdx.x;
  if (i < 128 * 67) {
    int o = i / 67, c = i % 67;
    w1t[c * 128 + o] = w1[i];
  }
  if (i < 256 * 128) {
    int o = i >> 7, c = i & 127;
    w2t[c * 256 + o] = w2[i];
  }
}

// ---------------- prep_t: transpose feat (B,C,N) -> FT (B,N,C) ----------------
// LDS-tiled 64x64 transpose: coalesced reads along n, coalesced 16B writes
// along c. Makes the group_mlp gather read contiguous 256 B per point.
__global__ __launch_bounds__(256) void prep_t_kernel(const float* __restrict__ feat,
                                                     float* __restrict__ FT) {
  const int b = blockIdx.x >> 7;          // 4 batches
  const int n0 = (blockIdx.x & 127) << 6; // 128 tiles of 64 n
  const int tid = threadIdx.x;
  __shared__ float T[64][65];

  const float* F = feat + (size_t)b * CIN * NPTS;
#pragma unroll
  for (int p = 0; p < 16; ++p) {
    int c = p * 4 + (tid >> 6), ln = tid & 63;
    T[c][ln] = F[(size_t)c * NPTS + n0 + ln];
  }
  __syncthreads();
  float* O = FT + (size_t)b * NPTS * CIN;
#pragma unroll
  for (int p = 0; p < 4; ++p) {
    int j = tid >> 2, q = (tid & 3) + p * 4;
    float4 v = make_float4(T[q * 4 + 0][j], T[q * 4 + 1][j],
                           T[q * 4 + 2][j], T[q * 4 + 3][j]);
    *(float4*)&O[(size_t)(n0 + j) * CIN + q * 4] = v;
  }
}

// ---------------- Morton sort (u32 keys, in-LDS bitonic) ----------------
__device__ inline uint32_t part1by2(uint32_t x) {
  x &= 1023u;
  x = (x | (x << 16)) & 0x030000FFu;
  x = (x | (x << 8))  & 0x0300F00Fu;
  x = (x | (x << 4))  & 0x030C30C3u;
  x = (x | (x << 2))  & 0x09249249u;
  return x;
}

__device__ inline uint32_t morton3(float x, float y, float z) {
  int qx = (int)((x + 16.f) * 32.f);
  int qy = (int)((y + 16.f) * 32.f);
  int qz = (int)((z + 16.f) * 32.f);
  qx = qx < 0 ? 0 : (qx > 1023 ? 1023 : qx);
  qy = qy < 0 ? 0 : (qy > 1023 ? 1023 : qy);
  qz = qz < 0 ? 0 : (qz > 1023 ? 1023 : qz);
  return part1by2((uint32_t)qx) | (part1by2((uint32_t)qy) << 1) | (part1by2((uint32_t)qz) << 2);
}

// key = (morton top 19 bits << 13) | idx. Sort order only affects clustering
// quality, never correctness (min-updates are exact & order-independent).
__global__ __launch_bounds__(1024) void sort_kernel(const float* __restrict__ xyz,
                                                    float4* __restrict__ sorted) {
  const int b = blockIdx.x;
  const int tid = threadIdx.x;
  const float* X = xyz + (size_t)b * NPTS * 3;
  __shared__ uint32_t S[NPTS];  // 32 KB

  for (int k = 0; k < 8; ++k) {
    int p = tid + (k << 10);
    uint32_t m = morton3(X[p * 3 + 0], X[p * 3 + 1], X[p * 3 + 2]);
    S[p] = ((m >> 11) << 13) | (uint32_t)p;
  }
  __syncthreads();
  for (unsigned k = 2; k <= NPTS; k <<= 1) {
    for (unsigned j = k >> 1; j > 0; j >>= 1) {
      for (int i = tid; i < NPTS; i += 1024) {
        int l = i ^ (int)j;
        if (l > i) {
          uint32_t a = S[i], c = S[l];
          bool sw = ((i & k) == 0) ? (a > c) : (a < c);
          if (sw) { S[i] = c; S[l] = a; }
        }
      }
      __syncthreads();
    }
  }
  for (int k = 0; k < 8; ++k) {
    int pos = tid + (k << 10);
    int o = (int)(S[pos] & 8191u);
    float4 v;
    v.x = X[o * 3 + 0]; v.y = X[o * 3 + 1]; v.z = X[o * 3 + 2];
    v.w = __int_as_float(o);
    sorted[(size_t)b * NPTS + pos] = v;
  }
}

// ---------------- FPS v7 (verified 1330 us, absmax 0.0 — do not touch) --------
// R8 lesson: point data in registers (LDS point arrays -> 32-way conflicts).
// R9 lesson: redundant parallel block-stage on all waves after ONE barrier
// beats a serialized leader stage between TWO barriers.
// Bit-exactness (verified absmax 0.0 in R2/R3/R6/R7/R10):
//  * min-updates use exact-rounded ((dx*dx+dy*dy)+dz*dz); order-independent.
//  * cluster skipped only if 0.9999-scaled conservative bbox lower bound
//    >= cluster max dmin -> skip provably a no-op.
//  * cached wave (wm,wi) reused only when NO lane of the wave burst.
//  * all dists nonneg f32, so u32 order == float order.
//  * tie-breaks -> smallest original index at every stage (numpy argmax).

#define DPP_ROR_U32_MAX(v)                                                       \
  {                                                                              \
    uint32_t _t;                                                                 \
    _t = (uint32_t)__builtin_amdgcn_update_dpp(0, (int)(v), 0x121, 0xF, 0xF, false); if (_t > (v)) (v) = _t; \
    _t = (uint32_t)__builtin_amdgcn_update_dpp(0, (int)(v), 0x122, 0xF, 0xF, false); if (_t > (v)) (v) = _t; \
    _t = (uint32_t)__builtin_amdgcn_update_dpp(0, (int)(v), 0x124, 0xF, 0xF, false); if (_t > (v)) (v) = _t; \
    _t = (uint32_t)__builtin_amdgcn_update_dpp(0, (int)(v), 0x128, 0xF, 0xF, false); if (_t > (v)) (v) = _t; \
  }

#define DPP_ROR_U32_MIN(v)                                                       \
  {                                                                              \
    uint32_t _t;                                                                 \
    _t = (uint32_t)__builtin_amdgcn_update_dpp(-1, (int)(v), 0x121, 0xF, 0xF, false); if (_t < (v)) (v) = _t; \
    _t = (uint32_t)__builtin_amdgcn_update_dpp(-1, (int)(v), 0x122, 0xF, 0xF, false); if (_t < (v)) (v) = _t; \
    _t = (uint32_t)__builtin_amdgcn_update_dpp(-1, (int)(v), 0x124, 0xF, 0xF, false); if (_t < (v)) (v) = _t; \
    _t = (uint32_t)__builtin_amdgcn_update_dpp(-1, (int)(v), 0x128, 0xF, 0xF, false); if (_t < (v)) (v) = _t; \
  }

#define CSWAP(i, j)                                                              \
  if (oid[i] > oid[j]) {                                                         \
    int _ti = oid[i]; oid[i] = oid[j]; oid[j] = _ti;                             \
    float _tf;                                                                   \
    _tf = px[i]; px[i] = px[j]; px[j] = _tf;                                     \
    _tf = py[i]; py[i] = py[j]; py[j] = _tf;                                     \
    _tf = pz[i]; pz[i] = pz[j]; pz[j] = _tf;                                     \
  }

__global__ __launch_bounds__(1024) void fps_kernel(const float* __restrict__ xyz,
                                                   const float4* __restrict__ sorted,
                                                   float* __restrict__ new_xyz) {
  const int b = blockIdx.x;
  const int tid = threadIdx.x;     // 0..1023
  const int lane = tid & 63;
  const int wv = tid >> 6;         // 0..15
  const float* X = xyz + (size_t)b * NPTS * 3;
  const float4* SP = sorted + (size_t)b * NPTS;

  __shared__ float XL[NPTS * 3];          // 96 KB coord table (winner lookup)
  __shared__ __align__(8) uint2 rec[2][16];

  for (int i = tid; i < NPTS * 3; i += 1024) XL[i] = X[i];

  float px[8], py[8], pz[8], dmin[8];
  int oid[8];
#pragma unroll
  for (int k = 0; k < 8; ++k) {
    float4 p = SP[tid * 8 + k];
    px[k] = p.x; py[k] = p.y; pz[k] = p.z;
    oid[k] = __float_as_int(p.w);
    dmin[k] = 1e10f;
  }
  CSWAP(0, 1) CSWAP(2, 3) CSWAP(4, 5) CSWAP(6, 7)
  CSWAP(0, 2) CSWAP(1, 3) CSWAP(4, 6) CSWAP(5, 7)
  CSWAP(1, 2) CSWAP(5, 6)
  CSWAP(0, 4) CSWAP(1, 5) CSWAP(2, 6) CSWAP(3, 7)
  CSWAP(2, 4) CSWAP(3, 5)
  CSWAP(1, 2) CSWAP(3, 4) CSWAP(5, 6)

  float bxmin = px[0], bxmax = px[0], bymin = py[0], bymax = py[0], bzmin = pz[0], bzmax = pz[0];
#pragma unroll
  for (int k = 1; k < 8; ++k) {
    bxmin = fminf(bxmin, px[k]); bxmax = fmaxf(bxmax, px[k]);
    bymin = fminf(bymin, py[k]); bymax = fmaxf(bymax, py[k]);
    bzmin = fminf(bzmin, pz[k]); bzmax = fmaxf(bzmax, pz[k]);
  }
  float cmaxv = 1e10f;
  int   cmaxi = oid[0];
  uint32_t wwm = 0u, wwi = 0u;

  float cx = X[0], cy = X[1], cz = X[2];
  if (tid == 0) {
    new_xyz[(size_t)b * NPT * 3 + 0] = cx;
    new_xyz[(size_t)b * NPT * 3 + 1] = cy;
    new_xyz[(size_t)b * NPT * 3 + 2] = cz;
  }
  __syncthreads();   // XL ready

  for (int t = 1; t < NPT; ++t) {
    float ex = fmaxf(fmaxf(bxmin - cx, cx - bxmax), 0.f);
    float ey = fmaxf(fmaxf(bymin - cy, cy - bymax), 0.f);
    float ez = fmaxf(fmaxf(bzmin - cz, cz - bzmax), 0.f);
    float dlb = (ex * ex + ey * ey + ez * ez) * 0.9999f;
    bool act = dlb < cmaxv;

    if (__ballot(act)) {
      if (act) {
        float mv = -1.0f; int mi = 0;
#pragma unroll
        for (int k = 0; k < 8; ++k) {
          float dx = px[k] - cx, dy = py[k] - cy, dz = pz[k] - cz;
          float d = __fadd_rn(__fadd_rn(__fmul_rn(dx, dx), __fmul_rn(dy, dy)), __fmul_rn(dz, dz));
          float dm = fminf(dmin[k], d);
          dmin[k] = dm;
          if (dm > mv) { mv = dm; mi = oid[k]; }
        }
        cmaxv = mv; cmaxi = mi;
      }
      uint32_t vb = __float_as_uint(cmaxv);
      uint32_t rm = vb;
      DPP_ROR_U32_MAX(rm)
      uint32_t m0 = (uint32_t)__builtin_amdgcn_readlane((int)rm, 0);
      uint32_t m1 = (uint32_t)__builtin_amdgcn_readlane((int)rm, 16);
      uint32_t m2 = (uint32_t)__builtin_amdgcn_readlane((int)rm, 32);
      uint32_t m3 = (uint32_t)__builtin_amdgcn_readlane((int)rm, 48);
      uint32_t wm = m0 > m1 ? m0 : m1;
      uint32_t wmb = m2 > m3 ? m2 : m3;
      wm = wm > wmb ? wm : wmb;
      unsigned long long em = __ballot(vb == wm);
      uint32_t wi;
      if (__popcll(em) == 1) {
        wi = (uint32_t)__builtin_amdgcn_readlane(cmaxi, __ffsll(em) - 1);
      } else {
        uint32_t ik = (vb == wm) ? (uint32_t)cmaxi : 0xFFFFFFFFu;
        DPP_ROR_U32_MIN(ik)
        uint32_t i0 = (uint32_t)__builtin_amdgcn_readlane((int)ik, 0);
        uint32_t i1 = (uint32_t)__builtin_amdgcn_readlane((int)ik, 16);
        uint32_t i2 = (uint32_t)__builtin_amdgcn_readlane((int)ik, 32);
        uint32_t i3 = (uint32_t)__builtin_amdgcn_readlane((int)ik, 48);
        wi = i0 < i1 ? i0 : i1;
        uint32_t wib = i2 < i3 ? i2 : i3;
        wi = wi < wib ? wi : wib;
      }
      wwm = wm; wwi = wi;
    }

    const int buf = t & 1;
    if (lane == 0) { rec[buf][wv].x = wwm; rec[buf][wv].y = wwi; }
    __syncthreads();

    uint2 r = rec[buf][lane & 15];
    uint32_t bm = r.x;
    DPP_ROR_U32_MAX(bm)
    uint32_t ci = (r.x == bm) ? r.y : 0xFFFFFFFFu;
    DPP_ROR_U32_MIN(ci)
    int sidx = __builtin_amdgcn_readfirstlane((int)ci);

    cx = XL[3 * sidx + 0];
    cy = XL[3 * sidx + 1];
    cz = XL[3 * sidx + 2];

    if (tid == 0) {
      float* o = new_xyz + ((size_t)b * NPT + t) * 3;
      o[0] = cx; o[1] = cy; o[2] = cz;
    }
  }
}

// ---------------- ball query: one wave per (b,s) ----------------
__global__ __launch_bounds__(256) void ballquery_kernel(const float* __restrict__ xyz,
                                                        const float* __restrict__ new_xyz,
                                                        int* __restrict__ idx_out) {
  const int w = blockIdx.x * 4 + (threadIdx.x >> 6);   // (b*2048 + s)
  const int lane = threadIdx.x & 63;
  const int b = w >> 11;
  const float* X = xyz + (size_t)b * NPTS * 3;
  const float cx = new_xyz[w * 3 + 0];
  const float cy = new_xyz[w * 3 + 1];
  const float cz = new_xyz[w * 3 + 2];
  int* out = idx_out + (size_t)w * NS;

  int found = 0;
  int first = -1;
  for (int base = 0; base < NPTS; base += 64) {
    const int p = base + lane;
    float x = X[p * 3 + 0], y = X[p * 3 + 1], z = X[p * 3 + 2];
    float dx = x - cx, dy = y - cy, dz = z - cz;
    float d2 = __fadd_rn(__fadd_rn(__fmul_rn(dx, dx), __fmul_rn(dy, dy)), __fmul_rn(dz, dz));
    unsigned long long mask = __ballot(d2 < R2);
    if (mask != 0ull && first < 0) first = base + __ffsll((unsigned long long)mask) - 1;
    if (found < NS) {
      if ((mask >> lane) & 1ull) {
        int rank = found + __popcll(mask & ((1ull << lane) - 1ull));
        if (rank < NS) out[rank] = p;
      }
    }
    found += __popcll(mask);
    if (found >= NS) break;
  }
  if (found < NS) {
    int pad = (first < 0) ? 0 : first;
    if (lane >= found && lane < NS) out[lane] = pad;
  }
}

// ---------------- group + MLP + maxpool: 2 centers per 512-thread block ------
// R11 change: feature gather reads FT (point-major) -> two coalesced float4
// per point (4 cache lines/point) instead of 64 scattered lines per channel
// row. LDS write conflicts (8-way) occur on only 8 instructions per block —
// off the hot loop. MLP math/order unchanged (verified absmax 0.0).
__global__ __launch_bounds__(512) void group_mlp_kernel(const float* __restrict__ xyz,
                                                        const float* __restrict__ FT,
                                                        const float* __restrict__ new_xyz,
                                                        const int* __restrict__ idx,
                                                        const float* __restrict__ w1t,
                                                        const float* __restrict__ b1,
                                                        const float* __restrict__ w2t,
                                                        const float* __restrict__ b2,
                                                        float* __restrict__ pooled) {
  const int blk = blockIdx.x;            // pair id: s-global = 2*blk, 2*blk+1
  const int b = blk >> 10;               // batch
  const int sin0 = (2 * blk) & 2047;     // s within batch
  const int tid = threadIdx.x;

  __shared__ __align__(16) float G[67 * 64];    // (C+3) x 64
  __shared__ __align__(16) float H1[128 * 64];  // 128 x 64
  __shared__ int   lidx[2 * NS];
  __shared__ float ctr[6];

  if (tid < 64) lidx[tid] = idx[(size_t)(2 * blk) * NS + tid];
  if (tid < 6)  ctr[tid] = new_xyz[(size_t)(2 * blk) * 3 + tid];
  __syncthreads();

  const float* Fp = FT + (size_t)b * NPTS * CIN;
  const float* X = xyz + (size_t)b * NPTS * 3;

  // feature rows 3..66: coalesced float4 gather from point-major FT
  {
    int j = tid >> 3, q = tid & 7;     // 64 points x 8 thread-chunks
    int p = lidx[j];
    const float4* row = (const float4*)(Fp + (size_t)p * CIN);
    float4 v0 = row[q * 2 + 0];
    float4 v1 = row[q * 2 + 1];
    float vs[8] = {v0.x, v0.y, v0.z, v0.w, v1.x, v1.y, v1.z, v1.w};
#pragma unroll
    for (int i = 0; i < 8; ++i)
      G[(3 + q * 8 + i) * 64 + j] = vs[i];
  }
  // xyz rows 0..2: relative coords
  if (tid < 192) {
    int c = tid >> 6, j = tid & 63;
    int p = lidx[j];
    G[c * 64 + j] = X[p * 3 + c] - ctr[(j >> 5) * 3 + c];
  }
  __syncthreads();

  // H1 = relu(W1 @ G + b1): 128 x 64, each thread 4o x 4j
  {
    const int oi = tid >> 4, ji = tid & 15;    // 32 oi x 16 ji
    const int o0 = oi * 4, j0 = ji * 4;
    float acc[4][4];
#pragma unroll
    for (int i = 0; i < 4; ++i)
#pragma unroll
      for (int jj = 0; jj < 4; ++jj) acc[i][jj] = 0.f;
#pragma unroll 4
    for (int c = 0; c < 67; ++c) {
      float4 g  = *(const float4*)&G[c * 64 + j0];
      float4 wf = *(const float4*)&w1t[c * 128 + o0];
      float ga[4] = {g.x, g.y, g.z, g.w};
      float wa[4] = {wf.x, wf.y, wf.z, wf.w};
#pragma unroll
      for (int i = 0; i < 4; ++i)
#pragma unroll
        for (int jj = 0; jj < 4; ++jj)
          acc[i][jj] = fmaf(wa[i], ga[jj], acc[i][jj]);
    }
    float4 bb = *(const float4*)&b1[o0];
    float ba[4] = {bb.x, bb.y, bb.z, bb.w};
#pragma unroll
    for (int i = 0; i < 4; ++i) {
      float4 h;
      h.x = fmaxf(acc[i][0] + ba[i], 0.f);
      h.y = fmaxf(acc[i][1] + ba[i], 0.f);
      h.z = fmaxf(acc[i][2] + ba[i], 0.f);
      h.w = fmaxf(acc[i][3] + ba[i], 0.f);
      *(float4*)&H1[(o0 + i) * 64 + j0] = h;
    }
  }
  __syncthreads();

  // H2 = relu(W2 @ H1 + b2): 256 x 64, each thread 8o x 4j, then maxpool
  {
    const int oi = tid >> 4, ji = tid & 15;    // 32 oi x 16 ji
    const int o0 = oi * 8, j0 = ji * 4;
    float acc[8][4];
#pragma unroll
    for (int i = 0; i < 8; ++i)
#pragma unroll
      for (int jj = 0; jj < 4; ++jj) acc[i][jj] = 0.f;
#pragma unroll 2
    for (int c = 0; c < 128; ++c) {
      float4 h  = *(const float4*)&H1[c * 64 + j0];
      float4 wa4 = *(const float4*)&w2t[c * 256 + o0];
      float4 wb4 = *(const float4*)&w2t[c * 256 + o0 + 4];
      float ha[4] = {h.x, h.y, h.z, h.w};
      float wa[8] = {wa4.x, wa4.y, wa4.z, wa4.w, wb4.x, wb4.y, wb4.z, wb4.w};
#pragma unroll
      for (int i = 0; i < 8; ++i)
#pragma unroll
        for (int jj = 0; jj < 4; ++jj)
          acc[i][jj] = fmaf(wa[i], ha[jj], acc[i][jj]);
    }
    float4 b2a = *(const float4*)&b2[o0];
    float4 b2b = *(const float4*)&b2[o0 + 4];
    float bb[8] = {b2a.x, b2a.y, b2a.z, b2a.w, b2b.x, b2b.y, b2b.z, b2b.w};
    float m[8];
#pragma unroll
    for (int i = 0; i < 8; ++i) {
      float v0 = fmaxf(acc[i][0] + bb[i], 0.f);
      float v1 = fmaxf(acc[i][1] + bb[i], 0.f);
      float v2 = fmaxf(acc[i][2] + bb[i], 0.f);
      float v3 = fmaxf(acc[i][3] + bb[i], 0.f);
      m[i] = fmaxf(fmaxf(v0, v1), fmaxf(v2, v3));
    }
    // ji 0..7 -> s0, ji 8..15 -> s1; xor 1,2,4 stays within each half
#pragma unroll
    for (int off = 1; off < 8; off <<= 1)
#pragma unroll
      for (int i = 0; i < 8; ++i) m[i] = fmaxf(m[i], __shfl_xor(m[i], off));
    const int ji_ = tid & 15;
    if (ji_ == 0 || ji_ == 8) {
      int sidx = sin0 + (ji_ >> 3);
#pragma unroll
      for (int i = 0; i < 8; ++i)
        pooled[((size_t)b * 256 + o0 + i) * (size_t)NPT + sidx] = m[i];
    }
  }
}

extern "C" void kernel_launch(void* const* d_in, const int* in_sizes, int n_in,
                              void* d_out, int out_size, void* d_ws, size_t ws_size,
                              hipStream_t stream) {
  (void)in_sizes; (void)n_in; (void)out_size; (void)ws_size;
  const float* xyz  = (const float*)d_in[0];   // (4,8192,3)
  const float* feat = (const float*)d_in[1];   // (4,64,8192)
  const float* w1   = (const float*)d_in[2];   // (128,67)
  const float* b1   = (const float*)d_in[3];   // (128)
  const float* w2   = (const float*)d_in[4];   // (256,128)
  const float* b2   = (const float*)d_in[5];   // (256)

  float* out     = (float*)d_out;
  float* new_xyz = out;                        // (4,2048,3)
  float* pooled  = out + (size_t)BATCH * NPT * 3;  // (4,256,2048)

  char* ws = (char*)d_ws;
  float*  w1t    = (float*)ws;                                   // 34304 B
  float*  w2t    = (float*)(ws + 34304);                         // 131072 B
  int*    idx    = (int*)(ws + 34304 + 131072);                  // 1048576 B
  float4* sorted = (float4*)(ws + 1213952);                      // 524288 B
  float*  FT     = (float*)(ws + 1738240);                       // 8388608 B (B,N,C)

  prep_kernel<<<128, 256, 0, stream>>>(w1, w2, w1t, w2t);
  prep_t_kernel<<<BATCH * 128, 256, 0, stream>>>(feat, FT);
  sort_kernel<<<BATCH, 1024, 0, stream>>>(xyz, sorted);
  fps_kernel<<<BATCH, 1024, 0, stream>>>(xyz, sorted, new_xyz);
  ballquery_kernel<<<(BATCH * NPT) / 4, 256, 0, stream>>>(xyz, new_xyz, idx);
  group_mlp_kernel<<<(BATCH * NPT) / 2, 512, 0, stream>>>(xyz, FT, new_xyz, idx,
                                                          w1t, b1, w2t, b2, pooled);
}

// Round 13
// 1686.889 us; speedup vs baseline: 2.5729x; 1.1399x over previous
//
#include <hip/hip_runtime.h>

// Problem constants (from reference)
#define NPTS   8192   // N
#define NPT    2048   // NPOINT
#define NS     32     // NSAMPLE
#define CIN    64
#define BATCH  4
// threshold: f32 nearest to 0.64 (numpy/jax weak-type the python float 0.8**2 to f32)
#define R2     0.64f

#define NWORK  252    // worker blocks (grid 256 = 4 fps + 252 workers = #CUs)
#define NQUAD  2048   // 8192 centers / 4 per quad

// ---------------- prep: transpose weights into ws ----------------
__global__ __launch_bounds__(256) void prep_kernel(const float* __restrict__ w1,
                                                   const float* __restrict__ w2,
                                                   float* __restrict__ w1t,
                                                   float* __restrict__ w2t) {
  int i = blockIdx.x * 256 + threadIdx.x;
  if (i < 128 * 67) {
    int o = i / 67, c = i % 67;
    w1t[c * 128 + o] = w1[i];
  }
  if (i < 256 * 128) {
    int o = i >> 7, c = i & 127;
    w2t[c * 256 + o] = w2[i];
  }
}

// ---------------- prep_t: transpose feat (B,C,N) -> FT (B,N,C) ----------------
__global__ __launch_bounds__(256) void prep_t_kernel(const float* __restrict__ feat,
                                                     float* __restrict__ FT) {
  const int b = blockIdx.x >> 7;
  const int n0 = (blockIdx.x & 127) << 6;
  const int tid = threadIdx.x;
  __shared__ float T[64][65];

  const float* F = feat + (size_t)b * CIN * NPTS;
#pragma unroll
  for (int p = 0; p < 16; ++p) {
    int c = p * 4 + (tid >> 6), ln = tid & 63;
    T[c][ln] = F[(size_t)c * NPTS + n0 + ln];
  }
  __syncthreads();
  float* O = FT + (size_t)b * NPTS * CIN;
#pragma unroll
  for (int p = 0; p < 4; ++p) {
    int j = tid >> 2, q = (tid & 3) + p * 4;
    float4 v = make_float4(T[q * 4 + 0][j], T[q * 4 + 1][j],
                           T[q * 4 + 2][j], T[q * 4 + 3][j]);
    *(float4*)&O[(size_t)(n0 + j) * CIN + q * 4] = v;
  }
}

// ---------------- Morton sort (u32 keys, in-LDS bitonic) ----------------
__device__ inline uint32_t part1by2(uint32_t x) {
  x &= 1023u;
  x = (x | (x << 16)) & 0x030000FFu;
  x = (x | (x << 8))  & 0x0300F00Fu;
  x = (x | (x << 4))  & 0x030C30C3u;
  x = (x | (x << 2))  & 0x09249249u;
  return x;
}

__device__ inline uint32_t morton3(float x, float y, float z) {
  int qx = (int)((x + 16.f) * 32.f);
  int qy = (int)((y + 16.f) * 32.f);
  int qz = (int)((z + 16.f) * 32.f);
  qx = qx < 0 ? 0 : (qx > 1023 ? 1023 : qx);
  qy = qy < 0 ? 0 : (qy > 1023 ? 1023 : qy);
  qz = qz < 0 ? 0 : (qz > 1023 ? 1023 : qz);
  return part1by2((uint32_t)qx) | (part1by2((uint32_t)qy) << 1) | (part1by2((uint32_t)qz) << 2);
}

__global__ __launch_bounds__(1024) void sort_kernel(const float* __restrict__ xyz,
                                                    float4* __restrict__ sorted) {
  const int b = blockIdx.x;
  const int tid = threadIdx.x;
  const float* X = xyz + (size_t)b * NPTS * 3;
  __shared__ uint32_t S[NPTS];  // 32 KB

  for (int k = 0; k < 8; ++k) {
    int p = tid + (k << 10);
    uint32_t m = morton3(X[p * 3 + 0], X[p * 3 + 1], X[p * 3 + 2]);
    S[p] = ((m >> 11) << 13) | (uint32_t)p;
  }
  __syncthreads();
  for (unsigned k = 2; k <= NPTS; k <<= 1) {
    for (unsigned j = k >> 1; j > 0; j >>= 1) {
      for (int i = tid; i < NPTS; i += 1024) {
        int l = i ^ (int)j;
        if (l > i) {
          uint32_t a = S[i], c = S[l];
          bool sw = ((i & k) == 0) ? (a > c) : (a < c);
          if (sw) { S[i] = c; S[l] = a; }
        }
      }
      __syncthreads();
    }
  }
  for (int k = 0; k < 8; ++k) {
    int pos = tid + (k << 10);
    int o = (int)(S[pos] & 8191u);
    float4 v;
    v.x = X[o * 3 + 0]; v.y = X[o * 3 + 1]; v.z = X[o * 3 + 2];
    v.w = __int_as_float(o);
    sorted[(size_t)b * NPTS + pos] = v;
  }
}

// ---------------- fused FPS + (ballquery + group + MLP + pool) workers --------
// Blocks 0..3: verified R7/R10 FPS loop (bit-exact, absmax 0.0), publishing
//   progress[b]=t (release, agent scope) every 16 centers.
// Blocks 4..255: persistent workers; each processes quads (4 centers) in
//   readiness order, spinning (acquire, agent scope) until fps has produced
//   its centers. Co-residency by construction: every block uses ~100 KB LDS
//   (> half of 160 KB) -> exactly 1 block/CU; grid 256 = #CUs -> all blocks
//   resident regardless of dispatch order (no deadlock).
// Exactness: fps math untouched; ballquery math identical (one wave per
//   center, ascending scan, pad-with-first); MLP identical per-thread tile
//   shapes (4ox4j / 8ox4j), fmaf order unchanged -> bit-identical results.

#define DPP_ROR_U32_MAX(v)                                                       \
  {                                                                              \
    uint32_t _t;                                                                 \
    _t = (uint32_t)__builtin_amdgcn_update_dpp(0, (int)(v), 0x121, 0xF, 0xF, false); if (_t > (v)) (v) = _t; \
    _t = (uint32_t)__builtin_amdgcn_update_dpp(0, (int)(v), 0x122, 0xF, 0xF, false); if (_t > (v)) (v) = _t; \
    _t = (uint32_t)__builtin_amdgcn_update_dpp(0, (int)(v), 0x124, 0xF, 0xF, false); if (_t > (v)) (v) = _t; \
    _t = (uint32_t)__builtin_amdgcn_update_dpp(0, (int)(v), 0x128, 0xF, 0xF, false); if (_t > (v)) (v) = _t; \
  }

#define DPP_ROR_U32_MIN(v)                                                       \
  {                                                                              \
    uint32_t _t;                                                                 \
    _t = (uint32_t)__builtin_amdgcn_update_dpp(-1, (int)(v), 0x121, 0xF, 0xF, false); if (_t < (v)) (v) = _t; \
    _t = (uint32_t)__builtin_amdgcn_update_dpp(-1, (int)(v), 0x122, 0xF, 0xF, false); if (_t < (v)) (v) = _t; \
    _t = (uint32_t)__builtin_amdgcn_update_dpp(-1, (int)(v), 0x124, 0xF, 0xF, false); if (_t < (v)) (v) = _t; \
    _t = (uint32_t)__builtin_amdgcn_update_dpp(-1, (int)(v), 0x128, 0xF, 0xF, false); if (_t < (v)) (v) = _t; \
  }

#define CSWAP(i, j)                                                              \
  if (oid[i] > oid[j]) {                                                         \
    int _ti = oid[i]; oid[i] = oid[j]; oid[j] = _ti;                             \
    float _tf;                                                                   \
    _tf = px[i]; px[i] = px[j]; px[j] = _tf;                                     \
    _tf = py[i]; py[i] = py[j]; py[j] = _tf;                                     \
    _tf = pz[i]; pz[i] = pz[j]; pz[j] = _tf;                                     \
  }

__global__ __launch_bounds__(1024, 1) void fused_kernel(
    const float* __restrict__ xyz, const float4* __restrict__ sorted,
    const float* __restrict__ FT,
    const float* __restrict__ w1t, const float* __restrict__ b1,
    const float* __restrict__ w2t, const float* __restrict__ b2,
    float* __restrict__ new_xyz, float* __restrict__ pooled,
    int* __restrict__ progress) {
  const int tid = threadIdx.x;
  const int lane = tid & 63;
  const int wv = tid >> 6;

  __shared__ __align__(16) char SM[100416];   // ~100 KB -> 1 block/CU

  if (blockIdx.x < 4) {
    // ================= FPS role (verified R7/R10 body) =================
    const int b = blockIdx.x;
    float* XL = (float*)SM;                   // 96 KB coord table
    uint2 (*rec)[16] = (uint2(*)[16])(SM + 98304);   // [2][16]
    const float* X = xyz + (size_t)b * NPTS * 3;
    const float4* SP = sorted + (size_t)b * NPTS;

    for (int i = tid; i < NPTS * 3; i += 1024) XL[i] = X[i];

    float px[8], py[8], pz[8], dmin[8];
    int oid[8];
#pragma unroll
    for (int k = 0; k < 8; ++k) {
      float4 p = SP[tid * 8 + k];
      px[k] = p.x; py[k] = p.y; pz[k] = p.z;
      oid[k] = __float_as_int(p.w);
      dmin[k] = 1e10f;
    }
    CSWAP(0, 1) CSWAP(2, 3) CSWAP(4, 5) CSWAP(6, 7)
    CSWAP(0, 2) CSWAP(1, 3) CSWAP(4, 6) CSWAP(5, 7)
    CSWAP(1, 2) CSWAP(5, 6)
    CSWAP(0, 4) CSWAP(1, 5) CSWAP(2, 6) CSWAP(3, 7)
    CSWAP(2, 4) CSWAP(3, 5)
    CSWAP(1, 2) CSWAP(3, 4) CSWAP(5, 6)

    float bxmin = px[0], bxmax = px[0], bymin = py[0], bymax = py[0], bzmin = pz[0], bzmax = pz[0];
#pragma unroll
    for (int k = 1; k < 8; ++k) {
      bxmin = fminf(bxmin, px[k]); bxmax = fmaxf(bxmax, px[k]);
      bymin = fminf(bymin, py[k]); bymax = fmaxf(bymax, py[k]);
      bzmin = fminf(bzmin, pz[k]); bzmax = fmaxf(bzmax, pz[k]);
    }
    float cmaxv = 1e10f;
    int   cmaxi = oid[0];
    uint32_t wwm = 0u, wwi = 0u;

    float cx = X[0], cy = X[1], cz = X[2];
    if (tid == 0) {
      new_xyz[(size_t)b * NPT * 3 + 0] = cx;
      new_xyz[(size_t)b * NPT * 3 + 1] = cy;
      new_xyz[(size_t)b * NPT * 3 + 2] = cz;
    }
    __syncthreads();   // XL ready

    for (int t = 1; t < NPT; ++t) {
      float ex = fmaxf(fmaxf(bxmin - cx, cx - bxmax), 0.f);
      float ey = fmaxf(fmaxf(bymin - cy, cy - bymax), 0.f);
      float ez = fmaxf(fmaxf(bzmin - cz, cz - bzmax), 0.f);
      float dlb = (ex * ex + ey * ey + ez * ez) * 0.9999f;
      bool act = dlb < cmaxv;

      if (__ballot(act)) {
        if (act) {
          float mv = -1.0f; int mi = 0;
#pragma unroll
          for (int k = 0; k < 8; ++k) {
            float dx = px[k] - cx, dy = py[k] - cy, dz = pz[k] - cz;
            float d = __fadd_rn(__fadd_rn(__fmul_rn(dx, dx), __fmul_rn(dy, dy)), __fmul_rn(dz, dz));
            float dm = fminf(dmin[k], d);
            dmin[k] = dm;
            if (dm > mv) { mv = dm; mi = oid[k]; }
          }
          cmaxv = mv; cmaxi = mi;
        }
        uint32_t vb = __float_as_uint(cmaxv);
        uint32_t rm = vb;
        DPP_ROR_U32_MAX(rm)
        uint32_t m0 = (uint32_t)__builtin_amdgcn_readlane((int)rm, 0);
        uint32_t m1 = (uint32_t)__builtin_amdgcn_readlane((int)rm, 16);
        uint32_t m2 = (uint32_t)__builtin_amdgcn_readlane((int)rm, 32);
        uint32_t m3 = (uint32_t)__builtin_amdgcn_readlane((int)rm, 48);
        uint32_t wm = m0 > m1 ? m0 : m1;
        uint32_t wmb = m2 > m3 ? m2 : m3;
        wm = wm > wmb ? wm : wmb;
        unsigned long long em = __ballot(vb == wm);
        uint32_t wi;
        if (__popcll(em) == 1) {
          wi = (uint32_t)__builtin_amdgcn_readlane(cmaxi, __ffsll(em) - 1);
        } else {
          uint32_t ik = (vb == wm) ? (uint32_t)cmaxi : 0xFFFFFFFFu;
          DPP_ROR_U32_MIN(ik)
          uint32_t i0 = (uint32_t)__builtin_amdgcn_readlane((int)ik, 0);
          uint32_t i1 = (uint32_t)__builtin_amdgcn_readlane((int)ik, 16);
          uint32_t i2 = (uint32_t)__builtin_amdgcn_readlane((int)ik, 32);
          uint32_t i3 = (uint32_t)__builtin_amdgcn_readlane((int)ik, 48);
          wi = i0 < i1 ? i0 : i1;
          uint32_t wib = i2 < i3 ? i2 : i3;
          wi = wi < wib ? wi : wib;
        }
        wwm = wm; wwi = wi;
      }

      const int buf = t & 1;
      if (lane == 0) { rec[buf][wv].x = wwm; rec[buf][wv].y = wwi; }
      __syncthreads();

      uint2 r = rec[buf][lane & 15];
      uint32_t bm = r.x;
      DPP_ROR_U32_MAX(bm)
      uint32_t ci = (r.x == bm) ? r.y : 0xFFFFFFFFu;
      DPP_ROR_U32_MIN(ci)
      int sidx = __builtin_amdgcn_readfirstlane((int)ci);

      cx = XL[3 * sidx + 0];
      cy = XL[3 * sidx + 1];
      cz = XL[3 * sidx + 2];

      if (tid == 0) {
        float* o = new_xyz + ((size_t)b * NPT + t) * 3;
        o[0] = cx; o[1] = cy; o[2] = cz;
        if ((t & 15) == 15)   // includes t=2047
          __hip_atomic_store(progress + b, t, __ATOMIC_RELEASE, __HIP_MEMORY_SCOPE_AGENT);
      }
    }
  } else {
    // ================= worker role: bq + group + MLP + pool =================
    float* G    = (float*)SM;                 // 67 x 128
    float* H1   = (float*)(SM + 34304);       // 128 x 128
    int*   lidx = (int*)(SM + 99840);         // 4 x 32
    float* ctr  = (float*)(SM + 100352);      // 4 x 3

    const int wbid = blockIdx.x - 4;          // 0..251

    for (int qg = wbid; qg < NQUAD; qg += NWORK) {
      const int b = qg & 3;                   // quads ordered by squad -> readiness-monotone
      const int s0 = (qg >> 2) * 4;           // first center (in-batch), 4 per quad
      const float* X  = xyz + (size_t)b * NPTS * 3;
      const float* Fp = FT + (size_t)b * NPTS * CIN;

      // 1) wait for fps to produce centers s0..s0+3
      if (tid == 0) {
        while (__hip_atomic_load(progress + b, __ATOMIC_ACQUIRE, __HIP_MEMORY_SCOPE_AGENT) < s0 + 3)
          __builtin_amdgcn_s_sleep(2);
      }
      __syncthreads();

      // 2) centers -> LDS; ball query: one wave per center (waves 0..3)
      if (tid < 12) ctr[tid] = new_xyz[((size_t)b * NPT + s0) * 3 + tid];
      if (wv < 4) {
        const int s = s0 + wv;
        const float cx = new_xyz[((size_t)b * NPT + s) * 3 + 0];
        const float cy = new_xyz[((size_t)b * NPT + s) * 3 + 1];
        const float cz = new_xyz[((size_t)b * NPT + s) * 3 + 2];
        int* out = lidx + wv * NS;
        int found = 0;
        int first = -1;
        for (int base = 0; base < NPTS; base += 64) {
          const int p = base + lane;
          float x = X[p * 3 + 0], y = X[p * 3 + 1], z = X[p * 3 + 2];
          float dx = x - cx, dy = y - cy, dz = z - cz;
          float d2 = __fadd_rn(__fadd_rn(__fmul_rn(dx, dx), __fmul_rn(dy, dy)), __fmul_rn(dz, dz));
          unsigned long long mask = __ballot(d2 < R2);
          if (mask != 0ull && first < 0) first = base + __ffsll((unsigned long long)mask) - 1;
          if (found < NS) {
            if ((mask >> lane) & 1ull) {
              int rank = found + __popcll(mask & ((1ull << lane) - 1ull));
              if (rank < NS) out[rank] = p;
            }
          }
          found += __popcll(mask);
          if (found >= NS) break;
        }
        if (found < NS) {
          int pad = (first < 0) ? 0 : first;
          if (lane >= found && lane < NS) out[lane] = pad;
        }
      }
      __syncthreads();

      // 3) G fill: feature rows via point-major FT (coalesced), rel-xyz rows
      {
        int j = tid >> 3, q = tid & 7;       // 128 points x 8 chunks
        int p = lidx[j];
        const float4* row = (const float4*)(Fp + (size_t)p * CIN);
        float4 v0 = row[q * 2 + 0];
        float4 v1 = row[q * 2 + 1];
        float vs[8] = {v0.x, v0.y, v0.z, v0.w, v1.x, v1.y, v1.z, v1.w};
#pragma unroll
        for (int i = 0; i < 8; ++i)
          G[(3 + q * 8 + i) * 128 + j] = vs[i];
      }
      if (tid < 384) {
        int c = tid >> 7, j = tid & 127;
        int p = lidx[j];
        G[c * 128 + j] = X[p * 3 + c] - ctr[(j >> 5) * 3 + c];
      }
      __syncthreads();

      // 4) H1 = relu(W1 @ G + b1): 128 x 128, each thread 4o x 4j
      {
        const int oi = tid >> 5, ji = tid & 31;
        const int o0 = oi * 4, j0 = ji * 4;
        float acc[4][4];
#pragma unroll
        for (int i = 0; i < 4; ++i)
#pragma unroll
          for (int jj = 0; jj < 4; ++jj) acc[i][jj] = 0.f;
#pragma unroll 4
        for (int c = 0; c < 67; ++c) {
          float4 g  = *(const float4*)&G[c * 128 + j0];
          float4 wf = *(const float4*)&w1t[c * 128 + o0];
          float ga[4] = {g.x, g.y, g.z, g.w};
          float wa[4] = {wf.x, wf.y, wf.z, wf.w};
#pragma unroll
          for (int i = 0; i < 4; ++i)
#pragma unroll
            for (int jj = 0; jj < 4; ++jj)
              acc[i][jj] = fmaf(wa[i], ga[jj], acc[i][jj]);
        }
        float4 bb = *(const float4*)&b1[o0];
        float ba[4] = {bb.x, bb.y, bb.z, bb.w};
#pragma unroll
        for (int i = 0; i < 4; ++i) {
          float4 h;
          h.x = fmaxf(acc[i][0] + ba[i], 0.f);
          h.y = fmaxf(acc[i][1] + ba[i], 0.f);
          h.z = fmaxf(acc[i][2] + ba[i], 0.f);
          h.w = fmaxf(acc[i][3] + ba[i], 0.f);
          *(float4*)&H1[(o0 + i) * 128 + j0] = h;
        }
      }
      __syncthreads();

      // 5) H2 = relu(W2 @ H1 + b2): 256 x 128, thread 8o x 4j, then maxpool
      {
        const int oi = tid >> 5, ji = tid & 31;
        const int o0 = oi * 8, j0 = ji * 4;
        float acc[8][4];
#pragma unroll
        for (int i = 0; i < 8; ++i)
#pragma unroll
          for (int jj = 0; jj < 4; ++jj) acc[i][jj] = 0.f;
#pragma unroll 2
        for (int c = 0; c < 128; ++c) {
          float4 h  = *(const float4*)&H1[c * 128 + j0];
          float4 wa4 = *(const float4*)&w2t[c * 256 + o0];
          float4 wb4 = *(const float4*)&w2t[c * 256 + o0 + 4];
          float ha[4] = {h.x, h.y, h.z, h.w};
          float wa[8] = {wa4.x, wa4.y, wa4.z, wa4.w, wb4.x, wb4.y, wb4.z, wb4.w};
#pragma unroll
          for (int i = 0; i < 8; ++i)
#pragma unroll
            for (int jj = 0; jj < 4; ++jj)
              acc[i][jj] = fmaf(wa[i], ha[jj], acc[i][jj]);
        }
        float4 b2a = *(const float4*)&b2[o0];
        float4 b2b = *(const float4*)&b2[o0 + 4];
        float bb[8] = {b2a.x, b2a.y, b2a.z, b2a.w, b2b.x, b2b.y, b2b.z, b2b.w};
        float m[8];
#pragma unroll
        for (int i = 0; i < 8; ++i) {
          float v0 = fmaxf(acc[i][0] + bb[i], 0.f);
          float v1 = fmaxf(acc[i][1] + bb[i], 0.f);
          float v2 = fmaxf(acc[i][2] + bb[i], 0.f);
          float v3 = fmaxf(acc[i][3] + bb[i], 0.f);
          m[i] = fmaxf(fmaxf(v0, v1), fmaxf(v2, v3));
        }
        // ji&7 groups (8 lanes x 4 j = 32 samples = one center); xor 1,2,4
        // stays within each 8-lane group.
#pragma unroll
        for (int off = 1; off < 8; off <<= 1)
#pragma unroll
          for (int i = 0; i < 8; ++i) m[i] = fmaxf(m[i], __shfl_xor(m[i], off));
        if ((ji & 7) == 0) {
          int sidx = s0 + (ji >> 3);
#pragma unroll
          for (int i = 0; i < 8; ++i)
            pooled[((size_t)b * 256 + o0 + i) * (size_t)NPT + sidx] = m[i];
        }
      }
    }
  }
}

extern "C" void kernel_launch(void* const* d_in, const int* in_sizes, int n_in,
                              void* d_out, int out_size, void* d_ws, size_t ws_size,
                              hipStream_t stream) {
  (void)in_sizes; (void)n_in; (void)out_size; (void)ws_size;
  const float* xyz  = (const float*)d_in[0];   // (4,8192,3)
  const float* feat = (const float*)d_in[1];   // (4,64,8192)
  const float* w1   = (const float*)d_in[2];   // (128,67)
  const float* b1   = (const float*)d_in[3];   // (128)
  const float* w2   = (const float*)d_in[4];   // (256,128)
  const float* b2   = (const float*)d_in[5];   // (256)

  float* out     = (float*)d_out;
  float* new_xyz = out;                        // (4,2048,3)
  float* pooled  = out + (size_t)BATCH * NPT * 3;  // (4,256,2048)

  char* ws = (char*)d_ws;
  float*  w1t      = (float*)ws;                       // 34304 B
  float*  w2t      = (float*)(ws + 34304);             // 131072 B -> 165376
  float4* sorted   = (float4*)(ws + 165376);           // 524288 B -> 689664
  float*  FT       = (float*)(ws + 689664);            // 8388608 B -> 9078272
  int*    progress = (int*)(ws + 9078272);             // 16 B

  prep_kernel<<<128, 256, 0, stream>>>(w1, w2, w1t, w2t);
  prep_t_kernel<<<BATCH * 128, 256, 0, stream>>>(feat, FT);
  sort_kernel<<<BATCH, 1024, 0, stream>>>(xyz, sorted);
  (void)hipMemsetAsync(progress, 0, 16, stream);
  fused_kernel<<<256, 1024, 0, stream>>>(xyz, sorted, FT, w1t, b1, w2t, b2,
                                         new_xyz, pooled, progress);
}